// Round 9
// baseline (864.160 us; speedup 1.0000x reference)
//
#include <hip/hip_runtime.h>

// ---------------------------------------------------------------------------
// GNN_Disentangle on MI355X. H=64 fixed. f32 throughout.
//
// Round-9 change: kill the hidden W-reload L1 tax in the GEMV family.
//   r8 proof: VGPR_Count=44 under a 128-cap -> allocator CHOSE to remat the
//   16 W buffer_load_dwordx4 per node; that is 16KB L1 read/node = 2.6GB
//   ~= 67us L1-BW-bound -- the constant 82us floor since round 2.
//   Fix (two independent levers):
//   (1) asm volatile("" : "+v"(w[j])) pins w[64] in VGPRs (anti-remat).
//   (2) 4-node batching: 4 rows/iter, 4 FMAs per w element -> even if (1)
//       failed, W traffic /4; with (1) it also gives 4 indep acc chains.
// Everything else identical to round 8.
// ---------------------------------------------------------------------------

#define GS_GRID 2048
#define GS_BLK  256

enum { A1_=0, A0_=64, C1_=128, C0_=192, D1_=256, D0_=320,
       S1_=384, Q1_=512, SC1_=640, SH1_=768,
       S2_=896, Q2_=960, SC2_=1024, SH2_=1088,
       GD1_=1152, GA1_=1216, G00_=1280, CST_FLOATS=2048 };

__device__ __forceinline__ float wave_sum64(float v) {
#pragma unroll
  for (int o = 32; o; o >>= 1) v += __shfl_xor(v, o, 64);
  return v;
}

__device__ __forceinline__ int rfl(int v) { return __builtin_amdgcn_readfirstlane(v); }

__device__ __forceinline__ float rlane(float v, int k) {
  return __int_as_float(__builtin_amdgcn_readlane(__float_as_int(v), k));
}

// ---------------- CSR build: bucketed counting sort ----------------
// bucket = dst >> 10; requires N <= 262144 (<=256 buckets).

__global__ __launch_bounds__(256) void hist_k(const int* __restrict__ ei,
                                              int* __restrict__ hist, int E) {
  __shared__ int h[256];
  const int t = threadIdx.x;
  h[t] = 0;
  __syncthreads();
  const int per = (E + gridDim.x - 1) / gridDim.x;
  const int beg = blockIdx.x * per, end = min(E, beg + per);
  for (int i = beg + t; i < end; i += 256)
    atomicAdd(&h[ei[E + i] >> 10], 1);
  __syncthreads();
  hist[blockIdx.x * 256 + t] = h[t];
}

__global__ void bscan_k(int* __restrict__ hist, int* __restrict__ bucketBase,
                        int* __restrict__ rowptrN, int E, int nblk) {
  const int t = threadIdx.x;      // bucket id
  int run = 0;
  for (int b = 0; b < nblk; ++b) {
    int v = hist[b * 256 + t];
    hist[b * 256 + t] = run;      // block-exclusive offset within bucket
    run += v;
  }
  __shared__ int sc[256];
  sc[t] = run; __syncthreads();
  for (int o = 1; o < 256; o <<= 1) {
    int x = sc[t]; if (t >= o) x += sc[t - o];
    __syncthreads(); sc[t] = x; __syncthreads();
  }
  bucketBase[t] = sc[t] - run;    // exclusive over buckets
  if (t == 255) { bucketBase[256] = sc[t]; rowptrN[0] = E; }
}

__global__ __launch_bounds__(256) void bucket_k(const int* __restrict__ ei,
                                                const int* __restrict__ hist,
                                                const int* __restrict__ bucketBase,
                                                int2* __restrict__ eb, int E) {
  __shared__ int cur[256];
  const int t = threadIdx.x;
  cur[t] = hist[blockIdx.x * 256 + t] + bucketBase[t];
  __syncthreads();
  const int per = (E + gridDim.x - 1) / gridDim.x;
  const int beg = blockIdx.x * per, end = min(E, beg + per);
  for (int i = beg + t; i < end; i += 256) {
    int s = ei[i], d = ei[E + i];
    int pos = atomicAdd(&cur[d >> 10], 1);
    eb[pos] = make_int2(s, d);
  }
}

__global__ __launch_bounds__(256) void csr_k(const int2* __restrict__ eb,
                                             const int* __restrict__ bucketBase,
                                             int* __restrict__ rowptr, float* __restrict__ dinv,
                                             int* __restrict__ col, int N) {
  __shared__ int cnt[1024];
  __shared__ int base[1024];
  __shared__ int red[256];
  const int t = threadIdx.x;
  const int k = blockIdx.x;
  const int nodeBeg = k << 10;
  const int segBeg = bucketBase[k], segEnd = bucketBase[k + 1];
#pragma unroll
  for (int j = t; j < 1024; j += 256) cnt[j] = 0;
  __syncthreads();
  for (int i = segBeg + t; i < segEnd; i += 256)
    atomicAdd(&cnt[eb[i].y & 1023], 1);
  __syncthreads();
  int c0 = cnt[4 * t], c1 = cnt[4 * t + 1], c2 = cnt[4 * t + 2], c3 = cnt[4 * t + 3];
  int ts = c0 + c1 + c2 + c3;
  red[t] = ts; __syncthreads();
  for (int o = 1; o < 256; o <<= 1) {
    int x = red[t]; if (t >= o) x += red[t - o];
    __syncthreads(); red[t] = x; __syncthreads();
  }
  int off = red[t] - ts;
  base[4 * t] = off;
  base[4 * t + 1] = off + c0;
  base[4 * t + 2] = off + c0 + c1;
  base[4 * t + 3] = off + c0 + c1 + c2;
#pragma unroll
  for (int u = 0; u < 4; ++u) {
    int j = 4 * t + u;
    int node = nodeBeg + j;
    if (node < N) {
      rowptr[node] = segBeg + base[j];
      dinv[node] = rsqrtf((float)(cnt[j] + 1));   // +1 self loop
    }
  }
  __syncthreads();
  cnt[4 * t] = base[4 * t]; cnt[4 * t + 1] = base[4 * t + 1];
  cnt[4 * t + 2] = base[4 * t + 2]; cnt[4 * t + 3] = base[4 * t + 3];
  __syncthreads();
  for (int i = segBeg + t; i < segEnd; i += 256) {
    int2 e = eb[i];
    int pos = atomicAdd(&cnt[e.y & 1023], 1);
    col[segBeg + pos] = e.x;
  }
}

// ---------------- tiny const GEMVs ----------------
__global__ void consts1_k(const float* __restrict__ pbtW, const float* __restrict__ pertW,
                          const float* __restrict__ pertB, const float* __restrict__ etW,
                          const float* __restrict__ basW, const float* __restrict__ basB,
                          const float* __restrict__ etB, float* __restrict__ cst) {
  int h = threadIdx.x;  // 64
  float a1 = 0, a0 = 0, c1 = 0, c0 = 0;
  for (int k = 0; k < 64; ++k) {
    float wp = pbtW[h * 128 + k];
    a1 = fmaf(wp, pertW[k], a1);
    a0 = fmaf(wp, pertB[k], a0);
    float we = etW[h * 128 + 64 + k];
    c1 = fmaf(we, basW[k], c1);
    c0 = fmaf(we, basB[k], c0);
  }
  cst[A1_ + h] = a1; cst[A0_ + h] = a0; cst[C1_ + h] = c1; cst[C0_ + h] = c0 + etB[h];
}

__global__ void consts2_k(const float* __restrict__ pbtW, const float* __restrict__ pbtB,
                          float* __restrict__ cst) {
  int h = threadIdx.x;  // 64
  float d1 = 0, d0 = 0;
  for (int k = 0; k < 64; ++k) {
    float w = pbtW[h * 128 + 64 + k];
    d1 = fmaf(w, cst[C1_ + k], d1);
    d0 = fmaf(w, cst[C0_ + k], d0);
  }
  cst[D1_ + h] = d1; cst[D0_ + h] = d0 + pbtB[h];
}

// gd1 = g1W@d1, ga1 = g1W@a1, g00 = g1W@(d0+a0)
__global__ void consts3_k(const float* __restrict__ g1W, float* __restrict__ cst) {
  int h = threadIdx.x;  // 64
  float gd1 = 0, ga1 = 0, g00 = 0;
  for (int k = 0; k < 64; ++k) {
    float w = g1W[h * 64 + k];
    gd1 = fmaf(w, cst[D1_ + k], gd1);
    ga1 = fmaf(w, cst[A1_ + k], ga1);
    g00 = fmaf(w, cst[D0_ + k] + cst[A0_ + k], g00);
  }
  cst[GD1_ + h] = gd1; cst[GA1_ + h] = ga1; cst[G00_ + h] = g00;
}

// ---------------- per-gene tables ----------------
template <bool NORM>
__global__ __launch_bounds__(256, 4) void geneT_k(const float* __restrict__ in,
                                                  const float* __restrict__ W, int ldw,
                                                  float* __restrict__ out, int NG) {
  const int lane = threadIdx.x & 63;
  const int wid = blockIdx.x * 4 + (threadIdx.x >> 6);
  const int nw = gridDim.x * 4;
  float w[64];
#pragma unroll
  for (int j = 0; j < 16; ++j) {
    float4 v = *reinterpret_cast<const float4*>(W + lane * ldw + 4 * j);
    w[4 * j] = v.x; w[4 * j + 1] = v.y; w[4 * j + 2] = v.z; w[4 * j + 3] = v.w;
  }
#pragma unroll
  for (int j = 0; j < 64; ++j) asm volatile("" : "+v"(w[j]));   // pin in VGPRs
  for (int g = wid; g < NG; g += nw) {
    float e = in[g * 64 + lane];
    if (NORM) {
      float sq = wave_sum64(e * e);
      float nrm = sqrtf(sq);
      float s = nrm > 1.f ? 1.f / nrm : 1.f;
      e *= s;
    }
    float acc = 0.f;
#pragma unroll
    for (int k = 0; k < 64; ++k) acc = fmaf(w[k], rlane(e, k), acc);
    out[g * 64 + lane] = acc;
  }
}

// ---------------- elementwise pb2 / m1 ----------------
__global__ __launch_bounds__(256) void h0m1_k(const float* __restrict__ x,
                                              const float* __restrict__ embT2,
                                              const float* __restrict__ embTm1,
                                              const float* __restrict__ dinv,
                                              const float* __restrict__ cst,
                                              float* __restrict__ pb2, float* __restrict__ m1,
                                              int N, int NG) {
  int total = N * 16;
  for (int idx = blockIdx.x * blockDim.x + threadIdx.x; idx < total;
       idx += gridDim.x * blockDim.x) {
    int n = idx >> 4, q = idx & 15;
    int g = n % NG;
    float x0 = x[2 * n], x1 = x[2 * n + 1], dn = dinv[n];
    float4 e2 = *reinterpret_cast<const float4*>(embT2 + g * 64 + q * 4);
    float4 em = *reinterpret_cast<const float4*>(embTm1 + g * 64 + q * 4);
    float4 d1 = *reinterpret_cast<const float4*>(cst + D1_ + q * 4);
    float4 d0 = *reinterpret_cast<const float4*>(cst + D0_ + q * 4);
    float4 gd1 = *reinterpret_cast<const float4*>(cst + GD1_ + q * 4);
    float4 ga1 = *reinterpret_cast<const float4*>(cst + GA1_ + q * 4);
    float4 g00 = *reinterpret_cast<const float4*>(cst + G00_ + q * 4);
    float4 pv, mv;
    pv.x = fmaf(x0, d1.x, e2.x + d0.x); pv.y = fmaf(x0, d1.y, e2.y + d0.y);
    pv.z = fmaf(x0, d1.z, e2.z + d0.z); pv.w = fmaf(x0, d1.w, e2.w + d0.w);
    mv.x = dn * (fmaf(x0, gd1.x, fmaf(x1, ga1.x, em.x + g00.x)));
    mv.y = dn * (fmaf(x0, gd1.y, fmaf(x1, ga1.y, em.y + g00.y)));
    mv.z = dn * (fmaf(x0, gd1.z, fmaf(x1, ga1.z, em.z + g00.z)));
    mv.w = dn * (fmaf(x0, gd1.w, fmaf(x1, ga1.w, em.w + g00.w)));
    reinterpret_cast<float4*>(pb2)[idx] = pv;
    reinterpret_cast<float4*>(m1)[idx] = mv;
  }
}

// ---------------- GEMV, register broadcast, 4-node batch, pinned W ---------
// out[n,lane] = W[lane,:]·in[n, inOff:inOff+64]. Wave loads 4 node rows
// coalesced; broadcast via readlane (VALU). w[64] pinned in VGPRs via empty
// asm (+v) so the allocator cannot rematerialize the W loads (r8: it chose
// VGPR=44 and re-read 16KB of W per node from L1 -> L1-BW-bound 82us).
template <int LDIN, bool BN, bool MUL_D, bool STATS>
__global__ __launch_bounds__(256, 4) void gemv64_k(const float* __restrict__ in, int inOff,
                                                   const float* __restrict__ W, int ldw,
                                                   const float* __restrict__ bias,
                                                   const float* __restrict__ bnsc,
                                                   const float* __restrict__ bnsh,
                                                   const float* __restrict__ addv,
                                                   const float* __restrict__ dinv,
                                                   float* __restrict__ out, int ldout,
                                                   float* __restrict__ sums,
                                                   float* __restrict__ sqs, int N) {
  const int lane = threadIdx.x & 63;
  const int wid = blockIdx.x * 4 + (threadIdx.x >> 6);
  const int nw = gridDim.x * 4;
  float w[64];
#pragma unroll
  for (int j = 0; j < 16; ++j) {
    float4 v = *reinterpret_cast<const float4*>(W + lane * ldw + 4 * j);
    w[4 * j] = v.x; w[4 * j + 1] = v.y; w[4 * j + 2] = v.z; w[4 * j + 3] = v.w;
  }
#pragma unroll
  for (int j = 0; j < 64; ++j) asm volatile("" : "+v"(w[j]));   // pin in VGPRs
  const float bb = bias ? bias[lane] : 0.f;
  float scl = 0.f, shl = 0.f;
  if (BN) { scl = bnsc[lane]; shl = bnsh[lane]; }
  float s = 0.f, q = 0.f;
  const int nquad = (N + 3) >> 2;
  for (int qi = wid; qi < nquad; qi += nw) {
    const int n0 = rfl(qi) << 2;
    const int r0 = n0;
    const int r1 = min(n0 + 1, N - 1);
    const int r2 = min(n0 + 2, N - 1);
    const int r3 = min(n0 + 3, N - 1);
    float v0 = in[(size_t)r0 * LDIN + inOff + lane];
    float v1 = in[(size_t)r1 * LDIN + inOff + lane];
    float v2 = in[(size_t)r2 * LDIN + inOff + lane];
    float v3 = in[(size_t)r3 * LDIN + inOff + lane];
    if (BN) {
      v0 = fmaxf(fmaf(v0, scl, shl), 0.f);
      v1 = fmaxf(fmaf(v1, scl, shl), 0.f);
      v2 = fmaxf(fmaf(v2, scl, shl), 0.f);
      v3 = fmaxf(fmaf(v3, scl, shl), 0.f);
    }
    float a0 = 0.f, a1 = 0.f, a2 = 0.f, a3 = 0.f;
#pragma unroll
    for (int k = 0; k < 64; ++k) {
      const float wk = w[k];
      a0 = fmaf(wk, rlane(v0, k), a0);
      a1 = fmaf(wk, rlane(v1, k), a1);
      a2 = fmaf(wk, rlane(v2, k), a2);
      a3 = fmaf(wk, rlane(v3, k), a3);
    }
    float av[4] = {a0, a1, a2, a3};
#pragma unroll
    for (int u = 0; u < 4; ++u) {
      const int n = n0 + u;
      if (n < N) {
        float acc = av[u];
        if (MUL_D) acc *= dinv[n];
        acc += bb;
        if (addv) acc += addv[(size_t)n * 64 + lane];
        out[(size_t)n * ldout + lane] = acc;
        if (STATS) { s += acc; q += acc * acc; }
      }
    }
  }
  if (STATS) {
    __shared__ float red[256];
    const int t = threadIdx.x;
    __syncthreads(); red[t] = s; __syncthreads();
    if (t < 64) atomicAdd(&sums[lane], red[t] + red[t + 64] + red[t + 128] + red[t + 192]);
    __syncthreads(); red[t] = q; __syncthreads();
    if (t < 64) atomicAdd(&sqs[lane], red[t] + red[t + 64] + red[t + 128] + red[t + 192]);
  }
}

// ---------------- CSR gather (GCN aggregate + bias + relu) ----------------
__global__ __launch_bounds__(256) void gather_k(const float* __restrict__ m,
                                                const int* __restrict__ rowptr,
                                                const int* __restrict__ col,
                                                const float* __restrict__ dinv,
                                                const float* __restrict__ bias,
                                                float* __restrict__ out, int N) {
  const int lane = threadIdx.x & 63;
  const int wid = blockIdx.x * 4 + (threadIdx.x >> 6);
  const int nw = gridDim.x * 4;
  const float b = bias[lane];
  for (int n = wid; n < N; n += nw) {
    const int nn = rfl(n);
    const float dn = dinv[nn];
    float acc = m[(size_t)nn * 64 + lane];   // self term (m' = dinv[n]*m[n])
    float acc2 = 0.f;
    const int beg = rfl(rowptr[nn]), end = rfl(rowptr[nn + 1]);
    for (int base = beg; base < end; base += 64) {
      const int rem = end - base;
      const int kk = rem < 64 ? rem : 64;
      int cv = (lane < kk) ? col[base + lane] : 0;   // coalesced chunk
      int k = 0;
      for (; k + 3 < kk; k += 4) {
        int i0 = __shfl(cv, k, 64), i1 = __shfl(cv, k + 1, 64);
        int i2 = __shfl(cv, k + 2, 64), i3 = __shfl(cv, k + 3, 64);
        float v0 = m[(size_t)i0 * 64 + lane];
        float v1 = m[(size_t)i1 * 64 + lane];
        float v2 = m[(size_t)i2 * 64 + lane];
        float v3 = m[(size_t)i3 * 64 + lane];
        acc += v0 + v2; acc2 += v1 + v3;
      }
      for (; k < kk; ++k) acc += m[(size_t)__shfl(cv, k, 64) * 64 + lane];
    }
    out[(size_t)nn * 64 + lane] = fmaxf(fmaf(dn, acc + acc2, b), 0.f);
  }
}

__global__ void bnparam_k(const float* __restrict__ sums, const float* __restrict__ sqs,
                          const float* __restrict__ g, const float* __restrict__ be,
                          float* __restrict__ scale, float* __restrict__ shift, int C,
                          float invN) {
  int t = threadIdx.x;
  if (t < C) {
    float mu = sums[t] * invN;
    float var = fmaxf(sqs[t] * invN - mu * mu, 0.f);
    float sc = g[t] * rsqrtf(var + 1e-5f);
    scale[t] = sc;
    shift[t] = be[t] - mu * sc;
  }
}

__global__ __launch_bounds__(256) void rec3_k(const float* __restrict__ z2,
                                              const float* __restrict__ scale,
                                              const float* __restrict__ shift,
                                              const float* __restrict__ W3,
                                              const float* __restrict__ b3,
                                              float* __restrict__ out, int N) {
  const int lane = threadIdx.x & 63;
  const int wid = blockIdx.x * 4 + (threadIdx.x >> 6);
  const int nw = gridDim.x * 4;
  const float sc = scale[lane], sh = shift[lane], w = W3[lane], b = b3[0];
  for (int n = wid; n < N; n += nw) {
    float v = z2[(size_t)n * 64 + lane];
    v = fmaxf(fmaf(v, sc, sh), 0.f) * w;
    v = wave_sum64(v);
    if (lane == 0) out[n] = v + b;
  }
}

// ---------------------------------------------------------------------------
extern "C" void kernel_launch(void* const* d_in, const int* in_sizes, int n_in,
                              void* d_out, int out_size, void* d_ws, size_t ws_size,
                              hipStream_t stream) {
  const float* x     = (const float*)d_in[0];
  const int*   ei    = (const int*)d_in[1];
  const float* pertW = (const float*)d_in[2];
  const float* pertB = (const float*)d_in[3];
  const float* basW  = (const float*)d_in[4];
  const float* basB  = (const float*)d_in[5];
  const float* embTb = (const float*)d_in[6];
  const float* etW   = (const float*)d_in[7];
  const float* etB   = (const float*)d_in[8];
  const float* pbtW  = (const float*)d_in[9];
  const float* pbtB  = (const float*)d_in[10];
  const float* g1W   = (const float*)d_in[11];
  const float* g1B   = (const float*)d_in[12];
  const float* g2W   = (const float*)d_in[13];
  const float* g2B   = (const float*)d_in[14];
  const float* rW1   = (const float*)d_in[15];
  const float* rb1   = (const float*)d_in[16];
  const float* rg1   = (const float*)d_in[17];
  const float* rbe1  = (const float*)d_in[18];
  const float* rW2   = (const float*)d_in[19];
  const float* rb2   = (const float*)d_in[20];
  const float* rg2   = (const float*)d_in[21];
  const float* rbe2  = (const float*)d_in[22];
  const float* rW3   = (const float*)d_in[23];
  const float* rb3   = (const float*)d_in[24];
  float* outp = (float*)d_out;

  const int N  = in_sizes[0] / 2;
  const int E  = in_sizes[1] / 2;
  const int NG = in_sizes[6] / 64;
  const int NB = (N + 1023) >> 10;   // bucket count, <= 256 for N <= 262144

  // ---- workspace layout (f32/int32, all 256B-aligned) ----
  char* p = (char*)d_ws;
  float* cst   = (float*)p; p += CST_FLOATS * 4;
  int*   hist  = (int*)p;   p += 256 * 256 * 4;
  int*   bb    = (int*)p;   p += 1024;            // 257 ints used
  int*   rowptr= (int*)p;   p += (size_t)(N + 64) * 4;
  float* dinv  = (float*)p; p += (size_t)N * 4;
  int*   col   = (int*)p;   p += (size_t)E * 4;
  float* embT  = (float*)p; p += (size_t)NG * 64 * 4;   // reused as embTm1
  float* embT2 = (float*)p; p += (size_t)NG * 64 * 4;
  float* pb2   = (float*)p; p += (size_t)N * 64 * 4;
  float* hb    = (float*)p; p += (size_t)N * 64 * 4;
  float* tmp1  = (float*)p; p += (size_t)N * 64 * 4;
  float* tmp2  = (float*)p; p += (size_t)N * 64 * 4;
  float* Z   = tmp1;          // [N,128] overlay on tmp1+tmp2 (contiguous)
  float* z2  = pb2;           // rec2 output (pb2 free after last pbt)
  float* prt = hb;            // rec2 partial (hb free after rec1 reads it)
  float* embTm1 = embT;       // embT dead after embT2 is built
  int2*  eb = (int2*)tmp2;    // bucket-sorted edges; dead before gather uses tmp2

  dim3 blk(GS_BLK), grid(GS_GRID);

  // ---- per-call init ----
  hipMemsetAsync(cst, 0, CST_FLOATS * 4, stream);   // also zeroes BN sums

  // ---- graph setup: bucketed counting sort -> CSR ----
  hist_k<<<256, 256, 0, stream>>>(ei, hist, E);
  bscan_k<<<1, 256, 0, stream>>>(hist, bb, rowptr + N, E, 256);
  bucket_k<<<256, 256, 0, stream>>>(ei, hist, bb, eb, E);
  csr_k<<<NB, 256, 0, stream>>>(eb, bb, rowptr, dinv, col, N);

  // ---- front-end algebra ----
  consts1_k<<<1, 64, 0, stream>>>(pbtW, pertW, pertB, etW, basW, basB, etB, cst);
  consts2_k<<<1, 64, 0, stream>>>(pbtW, pbtB, cst);
  consts3_k<<<1, 64, 0, stream>>>(g1W, cst);
  geneT_k<true><<<256, 256, 0, stream>>>(embTb, etW, 128, embT, NG);
  geneT_k<false><<<256, 256, 0, stream>>>(embT, pbtW + 64, 128, embT2, NG);
  geneT_k<false><<<256, 256, 0, stream>>>(embT2, g1W, 64, embTm1, NG);
  h0m1_k<<<grid, blk, 0, stream>>>(x, embT2, embTm1, dinv, cst, pb2, tmp1, N, NG);

  // ---- GCN layer 1 (m1 already in tmp1, dinv folded) ----
  gather_k<<<grid, blk, 0, stream>>>(tmp1, rowptr, col, dinv, g1B, tmp2, N);
  gemv64_k<64, false, false, false><<<grid, blk, 0, stream>>>(
      tmp2, 0, pbtW, 128, nullptr, nullptr, nullptr, pb2, nullptr, hb, 64,
      nullptr, nullptr, N);
  // ---- GCN layer 2 ----
  gemv64_k<64, false, true, false><<<grid, blk, 0, stream>>>(
      hb, 0, g2W, 64, nullptr, nullptr, nullptr, nullptr, dinv, tmp1, 64,
      nullptr, nullptr, N);
  gather_k<<<grid, blk, 0, stream>>>(tmp1, rowptr, col, dinv, g2B, tmp2, N);
  gemv64_k<64, false, false, false><<<grid, blk, 0, stream>>>(
      tmp2, 0, pbtW, 128, nullptr, nullptr, nullptr, pb2, nullptr, hb, 64,
      nullptr, nullptr, N);

  // ---- recovery MLP ----
  gemv64_k<64, false, false, true><<<grid, blk, 0, stream>>>(
      hb, 0, rW1, 64, rb1, nullptr, nullptr, nullptr, nullptr, Z, 128,
      cst + S1_, cst + Q1_, N);
  gemv64_k<64, false, false, true><<<grid, blk, 0, stream>>>(
      hb, 0, rW1 + 64 * 64, 64, rb1 + 64, nullptr, nullptr, nullptr, nullptr, Z + 64, 128,
      cst + S1_ + 64, cst + Q1_ + 64, N);
  bnparam_k<<<1, 128, 0, stream>>>(cst + S1_, cst + Q1_, rg1, rbe1,
                                   cst + SC1_, cst + SH1_, 128, 1.0f / (float)N);
  // rec2: BN+ReLU folded in-register (Z untouched in memory)
  gemv64_k<128, true, false, false><<<grid, blk, 0, stream>>>(
      Z, 0, rW2, 128, nullptr, cst + SC1_, cst + SH1_, nullptr, nullptr, prt, 64,
      nullptr, nullptr, N);
  gemv64_k<128, true, false, true><<<grid, blk, 0, stream>>>(
      Z, 64, rW2 + 64, 128, rb2, cst + SC1_ + 64, cst + SH1_ + 64, prt, nullptr, z2, 64,
      cst + S2_, cst + Q2_, N);
  bnparam_k<<<1, 64, 0, stream>>>(cst + S2_, cst + Q2_, rg2, rbe2,
                                  cst + SC2_, cst + SH2_, 64, 1.0f / (float)N);
  rec3_k<<<grid, blk, 0, stream>>>(z2, cst + SC2_, cst + SH2_, rW3, rb3, outp, N);
}

// Round 10
// 580.217 us; speedup vs baseline: 1.4894x; 1.4894x over previous
//
#include <hip/hip_runtime.h>

// ---------------------------------------------------------------------------
// GNN_Disentangle on MI355X. H=64 fixed. f32 throughout.
//
// Round-10 change: GEMV family -> gemmt_k, a register-tiled GEMM.
//   After r2/r5/r6/r7/r9 all "64 weights/lane + broadcast" forms converged to
//   ~82-91us (W-remat L1 tax or readlane/broadcast overhead), flip the layout:
//   block = 64ch x 128node tile, thread = 8ch x 4node micro-tile (32 loop-
//   carried accumulators). X staged TRANSPOSED in LDS [64][130], W in [64][68].
//   Inner k: 2 broadcast ds_read_b128 (W) + 2 conflict-free ds_read_b64 (X)
//   + 32 FMA per wave -- per-lane LDS reads, no broadcast serialization.
//   Output transposed via LDS [128][68] -> coalesced float4 stores. BN-on-
//   input at staging; bias/dinv/addv/BN-stats fused at copy-out.
// CSR build, gather, h0m1, geneT (r7 form), rec3 unchanged.
// ---------------------------------------------------------------------------

#define GS_GRID 2048
#define GS_BLK  256

enum { A1_=0, A0_=64, C1_=128, C0_=192, D1_=256, D0_=320,
       S1_=384, Q1_=512, SC1_=640, SH1_=768,
       S2_=896, Q2_=960, SC2_=1024, SH2_=1088,
       GD1_=1152, GA1_=1216, G00_=1280, CST_FLOATS=2048 };

__device__ __forceinline__ float wave_sum64(float v) {
#pragma unroll
  for (int o = 32; o; o >>= 1) v += __shfl_xor(v, o, 64);
  return v;
}

__device__ __forceinline__ int rfl(int v) { return __builtin_amdgcn_readfirstlane(v); }

__device__ __forceinline__ float rlane(float v, int k) {
  return __int_as_float(__builtin_amdgcn_readlane(__float_as_int(v), k));
}

// ---------------- CSR build: bucketed counting sort ----------------
// bucket = dst >> 10; requires N <= 262144 (<=256 buckets).

__global__ __launch_bounds__(256) void hist_k(const int* __restrict__ ei,
                                              int* __restrict__ hist, int E) {
  __shared__ int h[256];
  const int t = threadIdx.x;
  h[t] = 0;
  __syncthreads();
  const int per = (E + gridDim.x - 1) / gridDim.x;
  const int beg = blockIdx.x * per, end = min(E, beg + per);
  for (int i = beg + t; i < end; i += 256)
    atomicAdd(&h[ei[E + i] >> 10], 1);
  __syncthreads();
  hist[blockIdx.x * 256 + t] = h[t];
}

__global__ void bscan_k(int* __restrict__ hist, int* __restrict__ bucketBase,
                        int* __restrict__ rowptrN, int E, int nblk) {
  const int t = threadIdx.x;      // bucket id
  int run = 0;
  for (int b = 0; b < nblk; ++b) {
    int v = hist[b * 256 + t];
    hist[b * 256 + t] = run;      // block-exclusive offset within bucket
    run += v;
  }
  __shared__ int sc[256];
  sc[t] = run; __syncthreads();
  for (int o = 1; o < 256; o <<= 1) {
    int x = sc[t]; if (t >= o) x += sc[t - o];
    __syncthreads(); sc[t] = x; __syncthreads();
  }
  bucketBase[t] = sc[t] - run;    // exclusive over buckets
  if (t == 255) { bucketBase[256] = sc[t]; rowptrN[0] = E; }
}

__global__ __launch_bounds__(256) void bucket_k(const int* __restrict__ ei,
                                                const int* __restrict__ hist,
                                                const int* __restrict__ bucketBase,
                                                int2* __restrict__ eb, int E) {
  __shared__ int cur[256];
  const int t = threadIdx.x;
  cur[t] = hist[blockIdx.x * 256 + t] + bucketBase[t];
  __syncthreads();
  const int per = (E + gridDim.x - 1) / gridDim.x;
  const int beg = blockIdx.x * per, end = min(E, beg + per);
  for (int i = beg + t; i < end; i += 256) {
    int s = ei[i], d = ei[E + i];
    int pos = atomicAdd(&cur[d >> 10], 1);
    eb[pos] = make_int2(s, d);
  }
}

__global__ __launch_bounds__(256) void csr_k(const int2* __restrict__ eb,
                                             const int* __restrict__ bucketBase,
                                             int* __restrict__ rowptr, float* __restrict__ dinv,
                                             int* __restrict__ col, int N) {
  __shared__ int cnt[1024];
  __shared__ int base[1024];
  __shared__ int red[256];
  const int t = threadIdx.x;
  const int k = blockIdx.x;
  const int nodeBeg = k << 10;
  const int segBeg = bucketBase[k], segEnd = bucketBase[k + 1];
#pragma unroll
  for (int j = t; j < 1024; j += 256) cnt[j] = 0;
  __syncthreads();
  for (int i = segBeg + t; i < segEnd; i += 256)
    atomicAdd(&cnt[eb[i].y & 1023], 1);
  __syncthreads();
  int c0 = cnt[4 * t], c1 = cnt[4 * t + 1], c2 = cnt[4 * t + 2], c3 = cnt[4 * t + 3];
  int ts = c0 + c1 + c2 + c3;
  red[t] = ts; __syncthreads();
  for (int o = 1; o < 256; o <<= 1) {
    int x = red[t]; if (t >= o) x += red[t - o];
    __syncthreads(); red[t] = x; __syncthreads();
  }
  int off = red[t] - ts;
  base[4 * t] = off;
  base[4 * t + 1] = off + c0;
  base[4 * t + 2] = off + c0 + c1;
  base[4 * t + 3] = off + c0 + c1 + c2;
#pragma unroll
  for (int u = 0; u < 4; ++u) {
    int j = 4 * t + u;
    int node = nodeBeg + j;
    if (node < N) {
      rowptr[node] = segBeg + base[j];
      dinv[node] = rsqrtf((float)(cnt[j] + 1));   // +1 self loop
    }
  }
  __syncthreads();
  cnt[4 * t] = base[4 * t]; cnt[4 * t + 1] = base[4 * t + 1];
  cnt[4 * t + 2] = base[4 * t + 2]; cnt[4 * t + 3] = base[4 * t + 3];
  __syncthreads();
  for (int i = segBeg + t; i < segEnd; i += 256) {
    int2 e = eb[i];
    int pos = atomicAdd(&cnt[e.y & 1023], 1);
    col[segBeg + pos] = e.x;
  }
}

// ---------------- tiny const GEMVs ----------------
__global__ void consts1_k(const float* __restrict__ pbtW, const float* __restrict__ pertW,
                          const float* __restrict__ pertB, const float* __restrict__ etW,
                          const float* __restrict__ basW, const float* __restrict__ basB,
                          const float* __restrict__ etB, float* __restrict__ cst) {
  int h = threadIdx.x;  // 64
  float a1 = 0, a0 = 0, c1 = 0, c0 = 0;
  for (int k = 0; k < 64; ++k) {
    float wp = pbtW[h * 128 + k];
    a1 = fmaf(wp, pertW[k], a1);
    a0 = fmaf(wp, pertB[k], a0);
    float we = etW[h * 128 + 64 + k];
    c1 = fmaf(we, basW[k], c1);
    c0 = fmaf(we, basB[k], c0);
  }
  cst[A1_ + h] = a1; cst[A0_ + h] = a0; cst[C1_ + h] = c1; cst[C0_ + h] = c0 + etB[h];
}

__global__ void consts2_k(const float* __restrict__ pbtW, const float* __restrict__ pbtB,
                          float* __restrict__ cst) {
  int h = threadIdx.x;  // 64
  float d1 = 0, d0 = 0;
  for (int k = 0; k < 64; ++k) {
    float w = pbtW[h * 128 + 64 + k];
    d1 = fmaf(w, cst[C1_ + k], d1);
    d0 = fmaf(w, cst[C0_ + k], d0);
  }
  cst[D1_ + h] = d1; cst[D0_ + h] = d0 + pbtB[h];
}

// gd1 = g1W@d1, ga1 = g1W@a1, g00 = g1W@(d0+a0)
__global__ void consts3_k(const float* __restrict__ g1W, float* __restrict__ cst) {
  int h = threadIdx.x;  // 64
  float gd1 = 0, ga1 = 0, g00 = 0;
  for (int k = 0; k < 64; ++k) {
    float w = g1W[h * 64 + k];
    gd1 = fmaf(w, cst[D1_ + k], gd1);
    ga1 = fmaf(w, cst[A1_ + k], ga1);
    g00 = fmaf(w, cst[D0_ + k] + cst[A0_ + k], g00);
  }
  cst[GD1_ + h] = gd1; cst[GA1_ + h] = ga1; cst[G00_ + h] = g00;
}

// ---------------- per-gene tables (r7 form) ----------------
template <bool NORM>
__global__ __launch_bounds__(256) void geneT_k(const float* __restrict__ in,
                                               const float* __restrict__ W, int ldw,
                                               float* __restrict__ out, int NG) {
  const int lane = threadIdx.x & 63;
  const int wid = blockIdx.x * 4 + (threadIdx.x >> 6);
  const int nw = gridDim.x * 4;
  float w[64];
#pragma unroll
  for (int j = 0; j < 16; ++j) {
    float4 v = *reinterpret_cast<const float4*>(W + lane * ldw + 4 * j);
    w[4 * j] = v.x; w[4 * j + 1] = v.y; w[4 * j + 2] = v.z; w[4 * j + 3] = v.w;
  }
  for (int g = wid; g < NG; g += nw) {
    float e = in[g * 64 + lane];
    if (NORM) {
      float sq = wave_sum64(e * e);
      float nrm = sqrtf(sq);
      float s = nrm > 1.f ? 1.f / nrm : 1.f;
      e *= s;
    }
    float acc = 0.f;
#pragma unroll
    for (int k = 0; k < 64; ++k) acc = fmaf(w[k], rlane(e, k), acc);
    out[g * 64 + lane] = acc;
  }
}

// ---------------- elementwise pb2 / m1 ----------------
__global__ __launch_bounds__(256) void h0m1_k(const float* __restrict__ x,
                                              const float* __restrict__ embT2,
                                              const float* __restrict__ embTm1,
                                              const float* __restrict__ dinv,
                                              const float* __restrict__ cst,
                                              float* __restrict__ pb2, float* __restrict__ m1,
                                              int N, int NG) {
  int total = N * 16;
  for (int idx = blockIdx.x * blockDim.x + threadIdx.x; idx < total;
       idx += gridDim.x * blockDim.x) {
    int n = idx >> 4, q = idx & 15;
    int g = n % NG;
    float x0 = x[2 * n], x1 = x[2 * n + 1], dn = dinv[n];
    float4 e2 = *reinterpret_cast<const float4*>(embT2 + g * 64 + q * 4);
    float4 em = *reinterpret_cast<const float4*>(embTm1 + g * 64 + q * 4);
    float4 d1 = *reinterpret_cast<const float4*>(cst + D1_ + q * 4);
    float4 d0 = *reinterpret_cast<const float4*>(cst + D0_ + q * 4);
    float4 gd1 = *reinterpret_cast<const float4*>(cst + GD1_ + q * 4);
    float4 ga1 = *reinterpret_cast<const float4*>(cst + GA1_ + q * 4);
    float4 g00 = *reinterpret_cast<const float4*>(cst + G00_ + q * 4);
    float4 pv, mv;
    pv.x = fmaf(x0, d1.x, e2.x + d0.x); pv.y = fmaf(x0, d1.y, e2.y + d0.y);
    pv.z = fmaf(x0, d1.z, e2.z + d0.z); pv.w = fmaf(x0, d1.w, e2.w + d0.w);
    mv.x = dn * (fmaf(x0, gd1.x, fmaf(x1, ga1.x, em.x + g00.x)));
    mv.y = dn * (fmaf(x0, gd1.y, fmaf(x1, ga1.y, em.y + g00.y)));
    mv.z = dn * (fmaf(x0, gd1.z, fmaf(x1, ga1.z, em.z + g00.z)));
    mv.w = dn * (fmaf(x0, gd1.w, fmaf(x1, ga1.w, em.w + g00.w)));
    reinterpret_cast<float4*>(pb2)[idx] = pv;
    reinterpret_cast<float4*>(m1)[idx] = mv;
  }
}

// ---------------- register-tiled GEMM: out[n,c] = W[c,:]·in[n,:] -----------
// Tile: 64 channels x 128 nodes per block (256 threads). Thread micro-tile:
// 8 channels x 4 nodes (32 loop-carried accumulators). X staged transposed
// Xs[k][n] (stride 130: even -> b64-aligned; staging-write banks spread),
// W staged Ws[k][c] (stride 68: b128-aligned). Inner k: 2 broadcast b128 (W)
// + 2 conflict-free b64 (X) + 32 FMA. Output transposed back via LDS
// Os[n][c] (stride 68) -> coalesced float4 stores with fused epilogue.
#define XS_STRIDE 130
#define WS_STRIDE 68
#define OS_STRIDE 68
#define OS_WORDS  (128 * OS_STRIDE)          // 8704 (>= 64*XS_STRIDE = 8320)
#define WS_WORDS  (64 * WS_STRIDE)           // 4352
#define LDS_WORDS (OS_WORDS + WS_WORDS + 128)

template <int LDIN, bool BN, bool MUL_D, bool STATS>
__global__ __launch_bounds__(256, 4) void gemmt_k(const float* __restrict__ in, int inOff,
                                                  const float* __restrict__ W, int ldw,
                                                  const float* __restrict__ bias,
                                                  const float* __restrict__ bnsc,
                                                  const float* __restrict__ bnsh,
                                                  const float* __restrict__ addv,
                                                  const float* __restrict__ dinv,
                                                  float* __restrict__ out, int ldout,
                                                  float* __restrict__ sums,
                                                  float* __restrict__ sqs, int N) {
  __shared__ float lds[LDS_WORDS];
  float* Xs = lds;                       // [64][130] during compute; Os[128][68] after
  float* Ws = lds + OS_WORDS;            // [64][68]
  float* sred = lds + OS_WORDS + WS_WORDS;  // [128] (STATS only)
  const int t = threadIdx.x;
  const int base = blockIdx.x << 7;      // 128 nodes per tile
  if (STATS && t < 128) sred[t] = 0.f;

  // ---- stage W: Ws[k][c] = W[c][k], 4096 floats ----
#pragma unroll
  for (int c = 0; c < 16; ++c) {
    int lin = c * 256 + t;
    int cw = lin >> 6, kw = lin & 63;
    Ws[kw * WS_STRIDE + cw] = W[cw * ldw + kw];
  }
  // ---- stage X transposed: Xs[k][n] = f(in[base+n][inOff+k]), 8192 floats ----
#pragma unroll
  for (int c = 0; c < 8; ++c) {
    int lin = c * 256 + t;               // float4 index, 2048 total
    int nl = lin >> 4, k4 = lin & 15;
    int row = base + nl; if (row >= N) row = N - 1;
    float4 v = *reinterpret_cast<const float4*>(in + (size_t)row * LDIN + inOff + 4 * k4);
    if (BN) {
      float4 sc = *reinterpret_cast<const float4*>(bnsc + 4 * k4);
      float4 sh = *reinterpret_cast<const float4*>(bnsh + 4 * k4);
      v.x = fmaxf(fmaf(v.x, sc.x, sh.x), 0.f);
      v.y = fmaxf(fmaf(v.y, sc.y, sh.y), 0.f);
      v.z = fmaxf(fmaf(v.z, sc.z, sh.z), 0.f);
      v.w = fmaxf(fmaf(v.w, sc.w, sh.w), 0.f);
    }
    Xs[(4 * k4 + 0) * XS_STRIDE + nl] = v.x;
    Xs[(4 * k4 + 1) * XS_STRIDE + nl] = v.y;
    Xs[(4 * k4 + 2) * XS_STRIDE + nl] = v.z;
    Xs[(4 * k4 + 3) * XS_STRIDE + nl] = v.w;
  }
  __syncthreads();

  // ---- compute: thread = 8ch x 4n ----
  const int ng = t & 31;                 // nodes 2ng, 2ng+1, 2ng+64, 2ng+65
  const int c0 = (t >> 5) * 8;
  float acc[8][4];
#pragma unroll
  for (int i = 0; i < 8; ++i)
#pragma unroll
    for (int j = 0; j < 4; ++j) acc[i][j] = 0.f;
#pragma unroll 4
  for (int k = 0; k < 64; ++k) {
    float4 wa = *reinterpret_cast<const float4*>(Ws + k * WS_STRIDE + c0);
    float4 wb = *reinterpret_cast<const float4*>(Ws + k * WS_STRIDE + c0 + 4);
    float2 xa = *reinterpret_cast<const float2*>(Xs + k * XS_STRIDE + 2 * ng);
    float2 xb = *reinterpret_cast<const float2*>(Xs + k * XS_STRIDE + 2 * ng + 64);
    const float w8[8] = {wa.x, wa.y, wa.z, wa.w, wb.x, wb.y, wb.z, wb.w};
    const float x4[4] = {xa.x, xa.y, xb.x, xb.y};
#pragma unroll
    for (int ci = 0; ci < 8; ++ci)
#pragma unroll
      for (int xi = 0; xi < 4; ++xi)
        acc[ci][xi] = fmaf(w8[ci], x4[xi], acc[ci][xi]);
  }
  __syncthreads();

  // ---- transpose result via LDS: Os[n][c] ----
  const int nd[4] = {2 * ng, 2 * ng + 1, 2 * ng + 64, 2 * ng + 65};
#pragma unroll
  for (int ci = 0; ci < 8; ++ci) {
    Xs[nd[0] * OS_STRIDE + c0 + ci] = acc[ci][0];
    Xs[nd[1] * OS_STRIDE + c0 + ci] = acc[ci][1];
    Xs[nd[2] * OS_STRIDE + c0 + ci] = acc[ci][2];
    Xs[nd[3] * OS_STRIDE + c0 + ci] = acc[ci][3];
  }
  __syncthreads();

  // ---- copy-out: coalesced float4 stores + fused epilogue + stats ----
  const int q = t & 15;                  // channel quad 4q..4q+3
  float4 bb = make_float4(0.f, 0.f, 0.f, 0.f);
  if (bias) bb = *reinterpret_cast<const float4*>(bias + 4 * q);
  float4 s4 = make_float4(0.f, 0.f, 0.f, 0.f);
  float4 q4 = make_float4(0.f, 0.f, 0.f, 0.f);
#pragma unroll
  for (int c = 0; c < 8; ++c) {
    int nl = c * 16 + (t >> 4);
    int n = base + nl;
    if (n < N) {
      float4 o = *reinterpret_cast<const float4*>(Xs + nl * OS_STRIDE + 4 * q);
      if (MUL_D) {
        float dv = dinv[n];
        o.x *= dv; o.y *= dv; o.z *= dv; o.w *= dv;
      }
      o.x += bb.x; o.y += bb.y; o.z += bb.z; o.w += bb.w;
      if (addv) {
        float4 av = *reinterpret_cast<const float4*>(addv + (size_t)n * 64 + 4 * q);
        o.x += av.x; o.y += av.y; o.z += av.z; o.w += av.w;
      }
      *reinterpret_cast<float4*>(out + (size_t)n * ldout + 4 * q) = o;
      if (STATS) {
        s4.x += o.x; s4.y += o.y; s4.z += o.z; s4.w += o.w;
        q4.x += o.x * o.x; q4.y += o.y * o.y; q4.z += o.z * o.z; q4.w += o.w * o.w;
      }
    }
  }
  if (STATS) {
    atomicAdd(&sred[4 * q + 0], s4.x);
    atomicAdd(&sred[4 * q + 1], s4.y);
    atomicAdd(&sred[4 * q + 2], s4.z);
    atomicAdd(&sred[4 * q + 3], s4.w);
    atomicAdd(&sred[64 + 4 * q + 0], q4.x);
    atomicAdd(&sred[64 + 4 * q + 1], q4.y);
    atomicAdd(&sred[64 + 4 * q + 2], q4.z);
    atomicAdd(&sred[64 + 4 * q + 3], q4.w);
    __syncthreads();
    if (t < 64) {
      atomicAdd(&sums[t], sred[t]);
      atomicAdd(&sqs[t], sred[64 + t]);
    }
  }
}

// ---------------- CSR gather (GCN aggregate + bias + relu) ----------------
__global__ __launch_bounds__(256) void gather_k(const float* __restrict__ m,
                                                const int* __restrict__ rowptr,
                                                const int* __restrict__ col,
                                                const float* __restrict__ dinv,
                                                const float* __restrict__ bias,
                                                float* __restrict__ out, int N) {
  const int lane = threadIdx.x & 63;
  const int wid = blockIdx.x * 4 + (threadIdx.x >> 6);
  const int nw = gridDim.x * 4;
  const float b = bias[lane];
  for (int n = wid; n < N; n += nw) {
    const int nn = rfl(n);
    const float dn = dinv[nn];
    float acc = m[(size_t)nn * 64 + lane];   // self term (m' = dinv[n]*m[n])
    float acc2 = 0.f;
    const int beg = rfl(rowptr[nn]), end = rfl(rowptr[nn + 1]);
    for (int base = beg; base < end; base += 64) {
      const int rem = end - base;
      const int kk = rem < 64 ? rem : 64;
      int cv = (lane < kk) ? col[base + lane] : 0;   // coalesced chunk
      int k = 0;
      for (; k + 3 < kk; k += 4) {
        int i0 = __shfl(cv, k, 64), i1 = __shfl(cv, k + 1, 64);
        int i2 = __shfl(cv, k + 2, 64), i3 = __shfl(cv, k + 3, 64);
        float v0 = m[(size_t)i0 * 64 + lane];
        float v1 = m[(size_t)i1 * 64 + lane];
        float v2 = m[(size_t)i2 * 64 + lane];
        float v3 = m[(size_t)i3 * 64 + lane];
        acc += v0 + v2; acc2 += v1 + v3;
      }
      for (; k < kk; ++k) acc += m[(size_t)__shfl(cv, k, 64) * 64 + lane];
    }
    out[(size_t)nn * 64 + lane] = fmaxf(fmaf(dn, acc + acc2, b), 0.f);
  }
}

__global__ void bnparam_k(const float* __restrict__ sums, const float* __restrict__ sqs,
                          const float* __restrict__ g, const float* __restrict__ be,
                          float* __restrict__ scale, float* __restrict__ shift, int C,
                          float invN) {
  int t = threadIdx.x;
  if (t < C) {
    float mu = sums[t] * invN;
    float var = fmaxf(sqs[t] * invN - mu * mu, 0.f);
    float sc = g[t] * rsqrtf(var + 1e-5f);
    scale[t] = sc;
    shift[t] = be[t] - mu * sc;
  }
}

__global__ __launch_bounds__(256) void rec3_k(const float* __restrict__ z2,
                                              const float* __restrict__ scale,
                                              const float* __restrict__ shift,
                                              const float* __restrict__ W3,
                                              const float* __restrict__ b3,
                                              float* __restrict__ out, int N) {
  const int lane = threadIdx.x & 63;
  const int wid = blockIdx.x * 4 + (threadIdx.x >> 6);
  const int nw = gridDim.x * 4;
  const float sc = scale[lane], sh = shift[lane], w = W3[lane], b = b3[0];
  for (int n = wid; n < N; n += nw) {
    float v = z2[(size_t)n * 64 + lane];
    v = fmaxf(fmaf(v, sc, sh), 0.f) * w;
    v = wave_sum64(v);
    if (lane == 0) out[n] = v + b;
  }
}

// ---------------------------------------------------------------------------
extern "C" void kernel_launch(void* const* d_in, const int* in_sizes, int n_in,
                              void* d_out, int out_size, void* d_ws, size_t ws_size,
                              hipStream_t stream) {
  const float* x     = (const float*)d_in[0];
  const int*   ei    = (const int*)d_in[1];
  const float* pertW = (const float*)d_in[2];
  const float* pertB = (const float*)d_in[3];
  const float* basW  = (const float*)d_in[4];
  const float* basB  = (const float*)d_in[5];
  const float* embTb = (const float*)d_in[6];
  const float* etW   = (const float*)d_in[7];
  const float* etB   = (const float*)d_in[8];
  const float* pbtW  = (const float*)d_in[9];
  const float* pbtB  = (const float*)d_in[10];
  const float* g1W   = (const float*)d_in[11];
  const float* g1B   = (const float*)d_in[12];
  const float* g2W   = (const float*)d_in[13];
  const float* g2B   = (const float*)d_in[14];
  const float* rW1   = (const float*)d_in[15];
  const float* rb1   = (const float*)d_in[16];
  const float* rg1   = (const float*)d_in[17];
  const float* rbe1  = (const float*)d_in[18];
  const float* rW2   = (const float*)d_in[19];
  const float* rb2   = (const float*)d_in[20];
  const float* rg2   = (const float*)d_in[21];
  const float* rbe2  = (const float*)d_in[22];
  const float* rW3   = (const float*)d_in[23];
  const float* rb3   = (const float*)d_in[24];
  float* outp = (float*)d_out;

  const int N  = in_sizes[0] / 2;
  const int E  = in_sizes[1] / 2;
  const int NG = in_sizes[6] / 64;
  const int NB = (N + 1023) >> 10;   // bucket count, <= 256 for N <= 262144
  const int NT = (N + 127) >> 7;     // gemmt tiles

  // ---- workspace layout (f32/int32, all 256B-aligned) ----
  char* p = (char*)d_ws;
  float* cst   = (float*)p; p += CST_FLOATS * 4;
  int*   hist  = (int*)p;   p += 256 * 256 * 4;
  int*   bb    = (int*)p;   p += 1024;            // 257 ints used
  int*   rowptr= (int*)p;   p += (size_t)(N + 64) * 4;
  float* dinv  = (float*)p; p += (size_t)N * 4;
  int*   col   = (int*)p;   p += (size_t)E * 4;
  float* embT  = (float*)p; p += (size_t)NG * 64 * 4;   // reused as embTm1
  float* embT2 = (float*)p; p += (size_t)NG * 64 * 4;
  float* pb2   = (float*)p; p += (size_t)N * 64 * 4;
  float* hb    = (float*)p; p += (size_t)N * 64 * 4;
  float* tmp1  = (float*)p; p += (size_t)N * 64 * 4;
  float* tmp2  = (float*)p; p += (size_t)N * 64 * 4;
  float* Z   = tmp1;          // [N,128] overlay on tmp1+tmp2 (contiguous)
  float* z2  = pb2;           // rec2 output (pb2 free after last pbt)
  float* prt = hb;            // rec2 partial (hb free after rec1 reads it)
  float* embTm1 = embT;       // embT dead after embT2 is built
  int2*  eb = (int2*)tmp2;    // bucket-sorted edges; dead before gather uses tmp2

  dim3 blk(GS_BLK), grid(GS_GRID);

  // ---- per-call init ----
  hipMemsetAsync(cst, 0, CST_FLOATS * 4, stream);   // also zeroes BN sums

  // ---- graph setup: bucketed counting sort -> CSR ----
  hist_k<<<256, 256, 0, stream>>>(ei, hist, E);
  bscan_k<<<1, 256, 0, stream>>>(hist, bb, rowptr + N, E, 256);
  bucket_k<<<256, 256, 0, stream>>>(ei, hist, bb, eb, E);
  csr_k<<<NB, 256, 0, stream>>>(eb, bb, rowptr, dinv, col, N);

  // ---- front-end algebra ----
  consts1_k<<<1, 64, 0, stream>>>(pbtW, pertW, pertB, etW, basW, basB, etB, cst);
  consts2_k<<<1, 64, 0, stream>>>(pbtW, pbtB, cst);
  consts3_k<<<1, 64, 0, stream>>>(g1W, cst);
  geneT_k<true><<<256, 256, 0, stream>>>(embTb, etW, 128, embT, NG);
  geneT_k<false><<<256, 256, 0, stream>>>(embT, pbtW + 64, 128, embT2, NG);
  geneT_k<false><<<256, 256, 0, stream>>>(embT2, g1W, 64, embTm1, NG);
  h0m1_k<<<grid, blk, 0, stream>>>(x, embT2, embTm1, dinv, cst, pb2, tmp1, N, NG);

  // ---- GCN layer 1 (m1 already in tmp1, dinv folded) ----
  gather_k<<<grid, blk, 0, stream>>>(tmp1, rowptr, col, dinv, g1B, tmp2, N);
  gemmt_k<64, false, false, false><<<NT, blk, 0, stream>>>(
      tmp2, 0, pbtW, 128, nullptr, nullptr, nullptr, pb2, nullptr, hb, 64,
      nullptr, nullptr, N);
  // ---- GCN layer 2 ----
  gemmt_k<64, false, true, false><<<NT, blk, 0, stream>>>(
      hb, 0, g2W, 64, nullptr, nullptr, nullptr, nullptr, dinv, tmp1, 64,
      nullptr, nullptr, N);
  gather_k<<<grid, blk, 0, stream>>>(tmp1, rowptr, col, dinv, g2B, tmp2, N);
  gemmt_k<64, false, false, false><<<NT, blk, 0, stream>>>(
      tmp2, 0, pbtW, 128, nullptr, nullptr, nullptr, pb2, nullptr, hb, 64,
      nullptr, nullptr, N);

  // ---- recovery MLP ----
  gemmt_k<64, false, false, true><<<NT, blk, 0, stream>>>(
      hb, 0, rW1, 64, rb1, nullptr, nullptr, nullptr, nullptr, Z, 128,
      cst + S1_, cst + Q1_, N);
  gemmt_k<64, false, false, true><<<NT, blk, 0, stream>>>(
      hb, 0, rW1 + 64 * 64, 64, rb1 + 64, nullptr, nullptr, nullptr, nullptr, Z + 64, 128,
      cst + S1_ + 64, cst + Q1_ + 64, N);
  bnparam_k<<<1, 128, 0, stream>>>(cst + S1_, cst + Q1_, rg1, rbe1,
                                   cst + SC1_, cst + SH1_, 128, 1.0f / (float)N);
  // rec2: BN+ReLU on input applied at X staging (Z untouched in memory)
  gemmt_k<128, true, false, false><<<NT, blk, 0, stream>>>(
      Z, 0, rW2, 128, nullptr, cst + SC1_, cst + SH1_, nullptr, nullptr, prt, 64,
      nullptr, nullptr, N);
  gemmt_k<128, true, false, true><<<NT, blk, 0, stream>>>(
      Z, 64, rW2 + 64, 128, rb2, cst + SC1_ + 64, cst + SH1_ + 64, prt, nullptr, z2, 64,
      cst + S2_, cst + Q2_, N);
  bnparam_k<<<1, 64, 0, stream>>>(cst + S2_, cst + Q2_, rg2, rbe2,
                                  cst + SC2_, cst + SH2_, 64, 1.0f / (float)N);
  rec3_k<<<grid, blk, 0, stream>>>(z2, cst + SC2_, cst + SH2_, rW3, rb3, outp, N);
}

// Round 11
// 569.156 us; speedup vs baseline: 1.5183x; 1.0194x over previous
//
#include <hip/hip_runtime.h>

// ---------------------------------------------------------------------------
// GNN_Disentangle on MI355X. H=64 fixed. f32 throughout.
//
// Round-11 change: algebraic pass elimination around the r10 gemmt skeleton.
//   * layer-2 m fused: m2 = dinv*(Wf·t + gvec2[n]), Wf = g2W@pbtW_a,
//     gvec2 = embT2g2[g] + x0*(g2W@d1) + g2W@d0  -> pbt pass + hb killed.
//   * pbt folded into rec1: Z = Wr·t + gvecR[n] (+rb1), Wr = rW1@pbtW_a,
//     gvecR = embT2rA/B[g] + x0*(rW1@d1) + (rW1@d0 + rb1) -> pb2 killed.
//   * rec2: single kernel, K=128 via two stage+accumulate rounds (BN on
//     input at staging, bias + BN2 stats fused) -> prt round-trip killed.
//   7 gemm passes -> 4.2 equivalents; ~250MB intermediate traffic removed.
//   Z now overlays [hb,tmp1] (contiguous) so rec1 in (tmp2) never aliases out.
// CSR build, gather, geneT, rec3 unchanged from round 10.
// ---------------------------------------------------------------------------

#define GS_GRID 2048
#define GS_BLK  256

enum { A1_=0, A0_=64, C1_=128, C0_=192, D1_=256, D0_=320,
       S1_=384, Q1_=512, SC1_=640, SH1_=768,
       S2_=896, Q2_=960, SC2_=1024, SH2_=1088,
       GD1_=1152, GA1_=1216, G00_=1280,
       GD2_=1344, G02_=1408, RD1_=1472, RD0_=1600, CST_FLOATS=2048 };

__device__ __forceinline__ float wave_sum64(float v) {
#pragma unroll
  for (int o = 32; o; o >>= 1) v += __shfl_xor(v, o, 64);
  return v;
}

__device__ __forceinline__ int rfl(int v) { return __builtin_amdgcn_readfirstlane(v); }

__device__ __forceinline__ float rlane(float v, int k) {
  return __int_as_float(__builtin_amdgcn_readlane(__float_as_int(v), k));
}

// ---------------- CSR build: bucketed counting sort ----------------
// bucket = dst >> 10; requires N <= 262144 (<=256 buckets).

__global__ __launch_bounds__(256) void hist_k(const int* __restrict__ ei,
                                              int* __restrict__ hist, int E) {
  __shared__ int h[256];
  const int t = threadIdx.x;
  h[t] = 0;
  __syncthreads();
  const int per = (E + gridDim.x - 1) / gridDim.x;
  const int beg = blockIdx.x * per, end = min(E, beg + per);
  for (int i = beg + t; i < end; i += 256)
    atomicAdd(&h[ei[E + i] >> 10], 1);
  __syncthreads();
  hist[blockIdx.x * 256 + t] = h[t];
}

__global__ void bscan_k(int* __restrict__ hist, int* __restrict__ bucketBase,
                        int* __restrict__ rowptrN, int E, int nblk) {
  const int t = threadIdx.x;      // bucket id
  int run = 0;
  for (int b = 0; b < nblk; ++b) {
    int v = hist[b * 256 + t];
    hist[b * 256 + t] = run;      // block-exclusive offset within bucket
    run += v;
  }
  __shared__ int sc[256];
  sc[t] = run; __syncthreads();
  for (int o = 1; o < 256; o <<= 1) {
    int x = sc[t]; if (t >= o) x += sc[t - o];
    __syncthreads(); sc[t] = x; __syncthreads();
  }
  bucketBase[t] = sc[t] - run;    // exclusive over buckets
  if (t == 255) { bucketBase[256] = sc[t]; rowptrN[0] = E; }
}

__global__ __launch_bounds__(256) void bucket_k(const int* __restrict__ ei,
                                                const int* __restrict__ hist,
                                                const int* __restrict__ bucketBase,
                                                int2* __restrict__ eb, int E) {
  __shared__ int cur[256];
  const int t = threadIdx.x;
  cur[t] = hist[blockIdx.x * 256 + t] + bucketBase[t];
  __syncthreads();
  const int per = (E + gridDim.x - 1) / gridDim.x;
  const int beg = blockIdx.x * per, end = min(E, beg + per);
  for (int i = beg + t; i < end; i += 256) {
    int s = ei[i], d = ei[E + i];
    int pos = atomicAdd(&cur[d >> 10], 1);
    eb[pos] = make_int2(s, d);
  }
}

__global__ __launch_bounds__(256) void csr_k(const int2* __restrict__ eb,
                                             const int* __restrict__ bucketBase,
                                             int* __restrict__ rowptr, float* __restrict__ dinv,
                                             int* __restrict__ col, int N) {
  __shared__ int cnt[1024];
  __shared__ int base[1024];
  __shared__ int red[256];
  const int t = threadIdx.x;
  const int k = blockIdx.x;
  const int nodeBeg = k << 10;
  const int segBeg = bucketBase[k], segEnd = bucketBase[k + 1];
#pragma unroll
  for (int j = t; j < 1024; j += 256) cnt[j] = 0;
  __syncthreads();
  for (int i = segBeg + t; i < segEnd; i += 256)
    atomicAdd(&cnt[eb[i].y & 1023], 1);
  __syncthreads();
  int c0 = cnt[4 * t], c1 = cnt[4 * t + 1], c2 = cnt[4 * t + 2], c3 = cnt[4 * t + 3];
  int ts = c0 + c1 + c2 + c3;
  red[t] = ts; __syncthreads();
  for (int o = 1; o < 256; o <<= 1) {
    int x = red[t]; if (t >= o) x += red[t - o];
    __syncthreads(); red[t] = x; __syncthreads();
  }
  int off = red[t] - ts;
  base[4 * t] = off;
  base[4 * t + 1] = off + c0;
  base[4 * t + 2] = off + c0 + c1;
  base[4 * t + 3] = off + c0 + c1 + c2;
#pragma unroll
  for (int u = 0; u < 4; ++u) {
    int j = 4 * t + u;
    int node = nodeBeg + j;
    if (node < N) {
      rowptr[node] = segBeg + base[j];
      dinv[node] = rsqrtf((float)(cnt[j] + 1));   // +1 self loop
    }
  }
  __syncthreads();
  cnt[4 * t] = base[4 * t]; cnt[4 * t + 1] = base[4 * t + 1];
  cnt[4 * t + 2] = base[4 * t + 2]; cnt[4 * t + 3] = base[4 * t + 3];
  __syncthreads();
  for (int i = segBeg + t; i < segEnd; i += 256) {
    int2 e = eb[i];
    int pos = atomicAdd(&cnt[e.y & 1023], 1);
    col[segBeg + pos] = e.x;
  }
}

// ---------------- tiny const GEMVs ----------------
__global__ void consts1_k(const float* __restrict__ pbtW, const float* __restrict__ pertW,
                          const float* __restrict__ pertB, const float* __restrict__ etW,
                          const float* __restrict__ basW, const float* __restrict__ basB,
                          const float* __restrict__ etB, float* __restrict__ cst) {
  int h = threadIdx.x;  // 64
  float a1 = 0, a0 = 0, c1 = 0, c0 = 0;
  for (int k = 0; k < 64; ++k) {
    float wp = pbtW[h * 128 + k];
    a1 = fmaf(wp, pertW[k], a1);
    a0 = fmaf(wp, pertB[k], a0);
    float we = etW[h * 128 + 64 + k];
    c1 = fmaf(we, basW[k], c1);
    c0 = fmaf(we, basB[k], c0);
  }
  cst[A1_ + h] = a1; cst[A0_ + h] = a0; cst[C1_ + h] = c1; cst[C0_ + h] = c0 + etB[h];
}

__global__ void consts2_k(const float* __restrict__ pbtW, const float* __restrict__ pbtB,
                          float* __restrict__ cst) {
  int h = threadIdx.x;  // 64
  float d1 = 0, d0 = 0;
  for (int k = 0; k < 64; ++k) {
    float w = pbtW[h * 128 + 64 + k];
    d1 = fmaf(w, cst[C1_ + k], d1);
    d0 = fmaf(w, cst[C0_ + k], d0);
  }
  cst[D1_ + h] = d1; cst[D0_ + h] = d0 + pbtB[h];
}

// gd1 = g1W@d1, ga1 = g1W@a1, g00 = g1W@(d0+a0)   (layer-1 m, r4 fold)
__global__ void consts3_k(const float* __restrict__ g1W, float* __restrict__ cst) {
  int h = threadIdx.x;  // 64
  float gd1 = 0, ga1 = 0, g00 = 0;
  for (int k = 0; k < 64; ++k) {
    float w = g1W[h * 64 + k];
    gd1 = fmaf(w, cst[D1_ + k], gd1);
    ga1 = fmaf(w, cst[A1_ + k], ga1);
    g00 = fmaf(w, cst[D0_ + k] + cst[A0_ + k], g00);
  }
  cst[GD1_ + h] = gd1; cst[GA1_ + h] = ga1; cst[G00_ + h] = g00;
}

// GD2 = g2W@d1, G02 = g2W@d0   (layer-2 m fold)
__global__ void consts5_k(const float* __restrict__ g2W, float* __restrict__ cst) {
  int h = threadIdx.x;  // 64
  float a = 0, b = 0;
  for (int k = 0; k < 64; ++k) {
    float w = g2W[h * 64 + k];
    a = fmaf(w, cst[D1_ + k], a);
    b = fmaf(w, cst[D0_ + k], b);
  }
  cst[GD2_ + h] = a; cst[G02_ + h] = b;
}

// RD1 = rW1@d1, RD0 = rW1@d0 + rb1   (pbt-into-rec1 fold), 128 channels
__global__ void consts6_k(const float* __restrict__ rW1, const float* __restrict__ rb1,
                          float* __restrict__ cst) {
  int c = threadIdx.x;  // 128
  float a = 0, b = 0;
  for (int k = 0; k < 64; ++k) {
    float w = rW1[c * 64 + k];
    a = fmaf(w, cst[D1_ + k], a);
    b = fmaf(w, cst[D0_ + k], b);
  }
  cst[RD1_ + c] = a; cst[RD0_ + c] = b + rb1[c];
}

// Wf = g2W @ pbtW[:, :64]  (64x64); Wr = rW1 @ pbtW[:, :64]  (128x64)
__global__ void constsW_k(const float* __restrict__ g2W, const float* __restrict__ rW1,
                          const float* __restrict__ pbtW,
                          float* __restrict__ Wf, float* __restrict__ Wr) {
  const int t = threadIdx.x;
  for (int e = t; e < 4096; e += 256) {
    int c = e >> 6, j = e & 63;
    float s = 0.f;
    for (int h = 0; h < 64; ++h) s = fmaf(g2W[c * 64 + h], pbtW[h * 128 + j], s);
    Wf[e] = s;
  }
  for (int e = t; e < 8192; e += 256) {
    int c = e >> 6, j = e & 63;
    float s = 0.f;
    for (int h = 0; h < 64; ++h) s = fmaf(rW1[c * 64 + h], pbtW[h * 128 + j], s);
    Wr[e] = s;
  }
}

// ---------------- per-gene tables ----------------
template <bool NORM>
__global__ __launch_bounds__(256) void geneT_k(const float* __restrict__ in,
                                               const float* __restrict__ W, int ldw,
                                               float* __restrict__ out, int NG) {
  const int lane = threadIdx.x & 63;
  const int wid = blockIdx.x * 4 + (threadIdx.x >> 6);
  const int nw = gridDim.x * 4;
  float w[64];
#pragma unroll
  for (int j = 0; j < 16; ++j) {
    float4 v = *reinterpret_cast<const float4*>(W + lane * ldw + 4 * j);
    w[4 * j] = v.x; w[4 * j + 1] = v.y; w[4 * j + 2] = v.z; w[4 * j + 3] = v.w;
  }
  for (int g = wid; g < NG; g += nw) {
    float e = in[g * 64 + lane];
    if (NORM) {
      float sq = wave_sum64(e * e);
      float nrm = sqrtf(sq);
      float s = nrm > 1.f ? 1.f / nrm : 1.f;
      e *= s;
    }
    float acc = 0.f;
#pragma unroll
    for (int k = 0; k < 64; ++k) acc = fmaf(w[k], rlane(e, k), acc);
    out[g * 64 + lane] = acc;
  }
}

// ---------------- elementwise m1 ----------------
// m1 = dinv[n] * (embTm1[g] + x0*gd1 + x1*ga1 + g00)
__global__ __launch_bounds__(256) void m1_k(const float* __restrict__ x,
                                            const float* __restrict__ embTm1,
                                            const float* __restrict__ dinv,
                                            const float* __restrict__ cst,
                                            float* __restrict__ m1, int N, int NG) {
  int total = N * 16;
  for (int idx = blockIdx.x * blockDim.x + threadIdx.x; idx < total;
       idx += gridDim.x * blockDim.x) {
    int n = idx >> 4, q = idx & 15;
    int g = n % NG;
    float x0 = x[2 * n], x1 = x[2 * n + 1], dn = dinv[n];
    float4 em = *reinterpret_cast<const float4*>(embTm1 + g * 64 + q * 4);
    float4 gd1 = *reinterpret_cast<const float4*>(cst + GD1_ + q * 4);
    float4 ga1 = *reinterpret_cast<const float4*>(cst + GA1_ + q * 4);
    float4 g00 = *reinterpret_cast<const float4*>(cst + G00_ + q * 4);
    float4 mv;
    mv.x = dn * (fmaf(x0, gd1.x, fmaf(x1, ga1.x, em.x + g00.x)));
    mv.y = dn * (fmaf(x0, gd1.y, fmaf(x1, ga1.y, em.y + g00.y)));
    mv.z = dn * (fmaf(x0, gd1.z, fmaf(x1, ga1.z, em.z + g00.z)));
    mv.w = dn * (fmaf(x0, gd1.w, fmaf(x1, ga1.w, em.w + g00.w)));
    reinterpret_cast<float4*>(m1)[idx] = mv;
  }
}

// ---------------- register-tiled GEMM (r10 skeleton) ----------------
// Tile: 64 ch x 128 nodes, thread = 8ch x 4n micro-tile. X transposed in
// Xs[64][130], W in Ws[64][68], output transposed back via Os[128][68].
#define XS_STRIDE 130
#define WS_STRIDE 68
#define OS_STRIDE 68
#define OS_WORDS  (128 * OS_STRIDE)          // 8704 (>= 64*XS_STRIDE = 8320)
#define WS_WORDS  (64 * WS_STRIDE)           // 4352
#define LDS_WORDS (OS_WORDS + WS_WORDS + 128)

// gv variant: epilogue o = [dinv*] (acc + tbl[g] + x0*cA + cB); optional stats.
template <bool MUL_D, bool STATS>
__global__ __launch_bounds__(256, 4) void gemmt_gv_k(
    const float* __restrict__ in,        // [N,64]
    const float* __restrict__ W,         // [64][64] row-major
    const float* __restrict__ tbl,       // [NG,64]
    const float* __restrict__ cA,        // [64]
    const float* __restrict__ cB,        // [64]
    const float* __restrict__ x,         // [N,2]
    const float* __restrict__ dinv,
    float* __restrict__ out, int ldout,
    float* __restrict__ sums, float* __restrict__ sqs, int N, int NG) {
  __shared__ float lds[LDS_WORDS];
  float* Xs = lds;
  float* Ws = lds + OS_WORDS;
  float* sred = lds + OS_WORDS + WS_WORDS;
  const int t = threadIdx.x;
  const int base = blockIdx.x << 7;
  if (STATS && t < 128) sred[t] = 0.f;

#pragma unroll
  for (int c = 0; c < 16; ++c) {
    int lin = c * 256 + t;
    int cw = lin >> 6, kw = lin & 63;
    Ws[kw * WS_STRIDE + cw] = W[cw * 64 + kw];
  }
#pragma unroll
  for (int c = 0; c < 8; ++c) {
    int lin = c * 256 + t;
    int nl = lin >> 4, k4 = lin & 15;
    int row = base + nl; if (row >= N) row = N - 1;
    float4 v = *reinterpret_cast<const float4*>(in + (size_t)row * 64 + 4 * k4);
    Xs[(4 * k4 + 0) * XS_STRIDE + nl] = v.x;
    Xs[(4 * k4 + 1) * XS_STRIDE + nl] = v.y;
    Xs[(4 * k4 + 2) * XS_STRIDE + nl] = v.z;
    Xs[(4 * k4 + 3) * XS_STRIDE + nl] = v.w;
  }
  __syncthreads();

  const int ng = t & 31;
  const int c0 = (t >> 5) * 8;
  float acc[8][4];
#pragma unroll
  for (int i = 0; i < 8; ++i)
#pragma unroll
    for (int j = 0; j < 4; ++j) acc[i][j] = 0.f;
#pragma unroll 4
  for (int k = 0; k < 64; ++k) {
    float4 wa = *reinterpret_cast<const float4*>(Ws + k * WS_STRIDE + c0);
    float4 wb = *reinterpret_cast<const float4*>(Ws + k * WS_STRIDE + c0 + 4);
    float2 xa = *reinterpret_cast<const float2*>(Xs + k * XS_STRIDE + 2 * ng);
    float2 xb = *reinterpret_cast<const float2*>(Xs + k * XS_STRIDE + 2 * ng + 64);
    const float w8[8] = {wa.x, wa.y, wa.z, wa.w, wb.x, wb.y, wb.z, wb.w};
    const float x4[4] = {xa.x, xa.y, xb.x, xb.y};
#pragma unroll
    for (int ci = 0; ci < 8; ++ci)
#pragma unroll
      for (int xi = 0; xi < 4; ++xi)
        acc[ci][xi] = fmaf(w8[ci], x4[xi], acc[ci][xi]);
  }
  __syncthreads();

  const int nd[4] = {2 * ng, 2 * ng + 1, 2 * ng + 64, 2 * ng + 65};
#pragma unroll
  for (int ci = 0; ci < 8; ++ci) {
    Xs[nd[0] * OS_STRIDE + c0 + ci] = acc[ci][0];
    Xs[nd[1] * OS_STRIDE + c0 + ci] = acc[ci][1];
    Xs[nd[2] * OS_STRIDE + c0 + ci] = acc[ci][2];
    Xs[nd[3] * OS_STRIDE + c0 + ci] = acc[ci][3];
  }
  __syncthreads();

  const int q = t & 15;
  const float4 a4 = *reinterpret_cast<const float4*>(cA + 4 * q);
  const float4 b4 = *reinterpret_cast<const float4*>(cB + 4 * q);
  float4 s4 = make_float4(0.f, 0.f, 0.f, 0.f);
  float4 q4 = make_float4(0.f, 0.f, 0.f, 0.f);
#pragma unroll
  for (int c = 0; c < 8; ++c) {
    int nl = c * 16 + (t >> 4);
    int n = base + nl;
    if (n < N) {
      float4 o = *reinterpret_cast<const float4*>(Xs + nl * OS_STRIDE + 4 * q);
      int g = n % NG;
      float4 tg = *reinterpret_cast<const float4*>(tbl + (size_t)g * 64 + 4 * q);
      float x0 = x[2 * n];
      o.x += fmaf(x0, a4.x, tg.x + b4.x);
      o.y += fmaf(x0, a4.y, tg.y + b4.y);
      o.z += fmaf(x0, a4.z, tg.z + b4.z);
      o.w += fmaf(x0, a4.w, tg.w + b4.w);
      if (MUL_D) {
        float dv = dinv[n];
        o.x *= dv; o.y *= dv; o.z *= dv; o.w *= dv;
      }
      *reinterpret_cast<float4*>(out + (size_t)n * ldout + 4 * q) = o;
      if (STATS) {
        s4.x += o.x; s4.y += o.y; s4.z += o.z; s4.w += o.w;
        q4.x += o.x * o.x; q4.y += o.y * o.y; q4.z += o.z * o.z; q4.w += o.w * o.w;
      }
    }
  }
  if (STATS) {
    atomicAdd(&sred[4 * q + 0], s4.x);
    atomicAdd(&sred[4 * q + 1], s4.y);
    atomicAdd(&sred[4 * q + 2], s4.z);
    atomicAdd(&sred[4 * q + 3], s4.w);
    atomicAdd(&sred[64 + 4 * q + 0], q4.x);
    atomicAdd(&sred[64 + 4 * q + 1], q4.y);
    atomicAdd(&sred[64 + 4 * q + 2], q4.z);
    atomicAdd(&sred[64 + 4 * q + 3], q4.w);
    __syncthreads();
    if (t < 64) {
      atomicAdd(&sums[t], sred[t]);
      atomicAdd(&sqs[t], sred[64 + t]);
    }
  }
}

// rec2 variant: K=128 via two stage+accumulate rounds; BN+ReLU on input at
// staging; bias + BN2 stats fused at copy-out.
__global__ __launch_bounds__(256, 4) void gemmt_rec2_k(
    const float* __restrict__ Z,         // [N,128]
    const float* __restrict__ W,         // rW2 [64][128]
    const float* __restrict__ b,
    const float* __restrict__ bnsc, const float* __restrict__ bnsh,
    float* __restrict__ out,             // [N,64]
    float* __restrict__ sums, float* __restrict__ sqs, int N) {
  __shared__ float lds[LDS_WORDS];
  float* Xs = lds;
  float* Ws = lds + OS_WORDS;
  float* sred = lds + OS_WORDS + WS_WORDS;
  const int t = threadIdx.x;
  const int base = blockIdx.x << 7;
  if (t < 128) sred[t] = 0.f;

  const int ng = t & 31;
  const int c0 = (t >> 5) * 8;
  float acc[8][4];
#pragma unroll
  for (int i = 0; i < 8; ++i)
#pragma unroll
    for (int j = 0; j < 4; ++j) acc[i][j] = 0.f;

  for (int half = 0; half < 2; ++half) {
    if (half) __syncthreads();           // drain half-0 reads before overwrite
    const int ko = half * 64;
#pragma unroll
    for (int c = 0; c < 16; ++c) {
      int lin = c * 256 + t;
      int cw = lin >> 6, kw = lin & 63;
      Ws[kw * WS_STRIDE + cw] = W[cw * 128 + ko + kw];
    }
#pragma unroll
    for (int c = 0; c < 8; ++c) {
      int lin = c * 256 + t;
      int nl = lin >> 4, k4 = lin & 15;
      int row = base + nl; if (row >= N) row = N - 1;
      float4 v = *reinterpret_cast<const float4*>(Z + (size_t)row * 128 + ko + 4 * k4);
      float4 sc = *reinterpret_cast<const float4*>(bnsc + ko + 4 * k4);
      float4 sh = *reinterpret_cast<const float4*>(bnsh + ko + 4 * k4);
      v.x = fmaxf(fmaf(v.x, sc.x, sh.x), 0.f);
      v.y = fmaxf(fmaf(v.y, sc.y, sh.y), 0.f);
      v.z = fmaxf(fmaf(v.z, sc.z, sh.z), 0.f);
      v.w = fmaxf(fmaf(v.w, sc.w, sh.w), 0.f);
      Xs[(4 * k4 + 0) * XS_STRIDE + nl] = v.x;
      Xs[(4 * k4 + 1) * XS_STRIDE + nl] = v.y;
      Xs[(4 * k4 + 2) * XS_STRIDE + nl] = v.z;
      Xs[(4 * k4 + 3) * XS_STRIDE + nl] = v.w;
    }
    __syncthreads();
#pragma unroll 4
    for (int k = 0; k < 64; ++k) {
      float4 wa = *reinterpret_cast<const float4*>(Ws + k * WS_STRIDE + c0);
      float4 wb = *reinterpret_cast<const float4*>(Ws + k * WS_STRIDE + c0 + 4);
      float2 xa = *reinterpret_cast<const float2*>(Xs + k * XS_STRIDE + 2 * ng);
      float2 xb = *reinterpret_cast<const float2*>(Xs + k * XS_STRIDE + 2 * ng + 64);
      const float w8[8] = {wa.x, wa.y, wa.z, wa.w, wb.x, wb.y, wb.z, wb.w};
      const float x4[4] = {xa.x, xa.y, xb.x, xb.y};
#pragma unroll
      for (int ci = 0; ci < 8; ++ci)
#pragma unroll
        for (int xi = 0; xi < 4; ++xi)
          acc[ci][xi] = fmaf(w8[ci], x4[xi], acc[ci][xi]);
    }
  }
  __syncthreads();

  const int nd[4] = {2 * ng, 2 * ng + 1, 2 * ng + 64, 2 * ng + 65};
#pragma unroll
  for (int ci = 0; ci < 8; ++ci) {
    Xs[nd[0] * OS_STRIDE + c0 + ci] = acc[ci][0];
    Xs[nd[1] * OS_STRIDE + c0 + ci] = acc[ci][1];
    Xs[nd[2] * OS_STRIDE + c0 + ci] = acc[ci][2];
    Xs[nd[3] * OS_STRIDE + c0 + ci] = acc[ci][3];
  }
  __syncthreads();

  const int q = t & 15;
  const float4 bb = *reinterpret_cast<const float4*>(b + 4 * q);
  float4 s4 = make_float4(0.f, 0.f, 0.f, 0.f);
  float4 q4 = make_float4(0.f, 0.f, 0.f, 0.f);
#pragma unroll
  for (int c = 0; c < 8; ++c) {
    int nl = c * 16 + (t >> 4);
    int n = base + nl;
    if (n < N) {
      float4 o = *reinterpret_cast<const float4*>(Xs + nl * OS_STRIDE + 4 * q);
      o.x += bb.x; o.y += bb.y; o.z += bb.z; o.w += bb.w;
      *reinterpret_cast<float4*>(out + (size_t)n * 64 + 4 * q) = o;
      s4.x += o.x; s4.y += o.y; s4.z += o.z; s4.w += o.w;
      q4.x += o.x * o.x; q4.y += o.y * o.y; q4.z += o.z * o.z; q4.w += o.w * o.w;
    }
  }
  atomicAdd(&sred[4 * q + 0], s4.x);
  atomicAdd(&sred[4 * q + 1], s4.y);
  atomicAdd(&sred[4 * q + 2], s4.z);
  atomicAdd(&sred[4 * q + 3], s4.w);
  atomicAdd(&sred[64 + 4 * q + 0], q4.x);
  atomicAdd(&sred[64 + 4 * q + 1], q4.y);
  atomicAdd(&sred[64 + 4 * q + 2], q4.z);
  atomicAdd(&sred[64 + 4 * q + 3], q4.w);
  __syncthreads();
  if (t < 64) {
    atomicAdd(&sums[t], sred[t]);
    atomicAdd(&sqs[t], sred[64 + t]);
  }
}

// ---------------- CSR gather (GCN aggregate + bias + relu) ----------------
__global__ __launch_bounds__(256) void gather_k(const float* __restrict__ m,
                                                const int* __restrict__ rowptr,
                                                const int* __restrict__ col,
                                                const float* __restrict__ dinv,
                                                const float* __restrict__ bias,
                                                float* __restrict__ out, int N) {
  const int lane = threadIdx.x & 63;
  const int wid = blockIdx.x * 4 + (threadIdx.x >> 6);
  const int nw = gridDim.x * 4;
  const float b = bias[lane];
  for (int n = wid; n < N; n += nw) {
    const int nn = rfl(n);
    const float dn = dinv[nn];
    float acc = m[(size_t)nn * 64 + lane];   // self term (m' = dinv[n]*m[n])
    float acc2 = 0.f;
    const int beg = rfl(rowptr[nn]), end = rfl(rowptr[nn + 1]);
    for (int base = beg; base < end; base += 64) {
      const int rem = end - base;
      const int kk = rem < 64 ? rem : 64;
      int cv = (lane < kk) ? col[base + lane] : 0;   // coalesced chunk
      int k = 0;
      for (; k + 3 < kk; k += 4) {
        int i0 = __shfl(cv, k, 64), i1 = __shfl(cv, k + 1, 64);
        int i2 = __shfl(cv, k + 2, 64), i3 = __shfl(cv, k + 3, 64);
        float v0 = m[(size_t)i0 * 64 + lane];
        float v1 = m[(size_t)i1 * 64 + lane];
        float v2 = m[(size_t)i2 * 64 + lane];
        float v3 = m[(size_t)i3 * 64 + lane];
        acc += v0 + v2; acc2 += v1 + v3;
      }
      for (; k < kk; ++k) acc += m[(size_t)__shfl(cv, k, 64) * 64 + lane];
    }
    out[(size_t)nn * 64 + lane] = fmaxf(fmaf(dn, acc + acc2, b), 0.f);
  }
}

__global__ void bnparam_k(const float* __restrict__ sums, const float* __restrict__ sqs,
                          const float* __restrict__ g, const float* __restrict__ be,
                          float* __restrict__ scale, float* __restrict__ shift, int C,
                          float invN) {
  int t = threadIdx.x;
  if (t < C) {
    float mu = sums[t] * invN;
    float var = fmaxf(sqs[t] * invN - mu * mu, 0.f);
    float sc = g[t] * rsqrtf(var + 1e-5f);
    scale[t] = sc;
    shift[t] = be[t] - mu * sc;
  }
}

__global__ __launch_bounds__(256) void rec3_k(const float* __restrict__ z2,
                                              const float* __restrict__ scale,
                                              const float* __restrict__ shift,
                                              const float* __restrict__ W3,
                                              const float* __restrict__ b3,
                                              float* __restrict__ out, int N) {
  const int lane = threadIdx.x & 63;
  const int wid = blockIdx.x * 4 + (threadIdx.x >> 6);
  const int nw = gridDim.x * 4;
  const float sc = scale[lane], sh = shift[lane], w = W3[lane], b = b3[0];
  for (int n = wid; n < N; n += nw) {
    float v = z2[(size_t)n * 64 + lane];
    v = fmaxf(fmaf(v, sc, sh), 0.f) * w;
    v = wave_sum64(v);
    if (lane == 0) out[n] = v + b;
  }
}

// ---------------------------------------------------------------------------
extern "C" void kernel_launch(void* const* d_in, const int* in_sizes, int n_in,
                              void* d_out, int out_size, void* d_ws, size_t ws_size,
                              hipStream_t stream) {
  const float* x     = (const float*)d_in[0];
  const int*   ei    = (const int*)d_in[1];
  const float* pertW = (const float*)d_in[2];
  const float* pertB = (const float*)d_in[3];
  const float* basW  = (const float*)d_in[4];
  const float* basB  = (const float*)d_in[5];
  const float* embTb = (const float*)d_in[6];
  const float* etW   = (const float*)d_in[7];
  const float* etB   = (const float*)d_in[8];
  const float* pbtW  = (const float*)d_in[9];
  const float* pbtB  = (const float*)d_in[10];
  const float* g1W   = (const float*)d_in[11];
  const float* g1B   = (const float*)d_in[12];
  const float* g2W   = (const float*)d_in[13];
  const float* g2B   = (const float*)d_in[14];
  const float* rW1   = (const float*)d_in[15];
  const float* rb1   = (const float*)d_in[16];
  const float* rg1   = (const float*)d_in[17];
  const float* rbe1  = (const float*)d_in[18];
  const float* rW2   = (const float*)d_in[19];
  const float* rb2   = (const float*)d_in[20];
  const float* rg2   = (const float*)d_in[21];
  const float* rbe2  = (const float*)d_in[22];
  const float* rW3   = (const float*)d_in[23];
  const float* rb3   = (const float*)d_in[24];
  float* outp = (float*)d_out;

  const int N  = in_sizes[0] / 2;
  const int E  = in_sizes[1] / 2;
  const int NG = in_sizes[6] / 64;
  const int NB = (N + 1023) >> 10;   // bucket count, <= 256 for N <= 262144
  const int NT = (N + 127) >> 7;     // gemmt tiles

  // ---- workspace layout (f32/int32, all 256B-aligned) ----
  char* p = (char*)d_ws;
  float* cst    = (float*)p; p += CST_FLOATS * 4;
  int*   hist   = (int*)p;   p += 256 * 256 * 4;
  int*   bb     = (int*)p;   p += 1024;            // 257 ints used
  int*   rowptr = (int*)p;   p += (size_t)(N + 64) * 4;
  float* dinv   = (float*)p; p += (size_t)N * 4;
  int*   col    = (int*)p;   p += (size_t)E * 4;
  float* Wf     = (float*)p; p += 4096 * 4;        // g2W @ pbtW_a
  float* Wr     = (float*)p; p += 8192 * 4;        // rW1 @ pbtW_a
  float* embT   = (float*)p; p += (size_t)NG * 64 * 4;   // reused as embTm1
  float* embT2  = (float*)p; p += (size_t)NG * 64 * 4;
  float* embT2g2= (float*)p; p += (size_t)NG * 64 * 4;
  float* embT2rA= (float*)p; p += (size_t)NG * 64 * 4;
  float* embT2rB= (float*)p; p += (size_t)NG * 64 * 4;
  float* z2buf  = (float*)p; p += (size_t)N * 64 * 4;
  float* hb     = (float*)p; p += (size_t)N * 64 * 4;
  float* tmp1   = (float*)p; p += (size_t)N * 64 * 4;
  float* tmp2   = (float*)p; p += (size_t)N * 64 * 4;
  float* Z = hb;              // [N,128] overlay on hb+tmp1 (contiguous);
                              // input tmp2 never aliases Z (no race)
  float* z2 = z2buf;
  float* embTm1 = embT;       // embT dead after embT2 is built
  int2*  eb = (int2*)tmp2;    // bucket-sorted edges; dead before gather uses tmp2

  dim3 blk(GS_BLK), grid(GS_GRID);

  // ---- per-call init ----
  hipMemsetAsync(cst, 0, CST_FLOATS * 4, stream);   // also zeroes BN sums

  // ---- graph setup: bucketed counting sort -> CSR ----
  hist_k<<<256, 256, 0, stream>>>(ei, hist, E);
  bscan_k<<<1, 256, 0, stream>>>(hist, bb, rowptr + N, E, 256);
  bucket_k<<<256, 256, 0, stream>>>(ei, hist, bb, eb, E);
  csr_k<<<NB, 256, 0, stream>>>(eb, bb, rowptr, dinv, col, N);

  // ---- front-end algebra ----
  consts1_k<<<1, 64, 0, stream>>>(pbtW, pertW, pertB, etW, basW, basB, etB, cst);
  consts2_k<<<1, 64, 0, stream>>>(pbtW, pbtB, cst);
  consts3_k<<<1, 64, 0, stream>>>(g1W, cst);
  consts5_k<<<1, 64, 0, stream>>>(g2W, cst);
  consts6_k<<<1, 128, 0, stream>>>(rW1, rb1, cst);
  constsW_k<<<1, 256, 0, stream>>>(g2W, rW1, pbtW, Wf, Wr);
  geneT_k<true><<<256, 256, 0, stream>>>(embTb, etW, 128, embT, NG);
  geneT_k<false><<<256, 256, 0, stream>>>(embT, pbtW + 64, 128, embT2, NG);
  geneT_k<false><<<256, 256, 0, stream>>>(embT2, g1W, 64, embTm1, NG);
  geneT_k<false><<<256, 256, 0, stream>>>(embT2, g2W, 64, embT2g2, NG);
  geneT_k<false><<<256, 256, 0, stream>>>(embT2, rW1, 64, embT2rA, NG);
  geneT_k<false><<<256, 256, 0, stream>>>(embT2, rW1 + 64 * 64, 64, embT2rB, NG);
  m1_k<<<grid, blk, 0, stream>>>(x, embTm1, dinv, cst, tmp1, N, NG);

  // ---- GCN layer 1 aggregate ----
  gather_k<<<grid, blk, 0, stream>>>(tmp1, rowptr, col, dinv, g1B, tmp2, N);
  // ---- fused pbt+GCN2-m: m2 = dinv*(Wf·t + embT2g2[g] + x0*GD2 + G02) ----
  gemmt_gv_k<true, false><<<NT, blk, 0, stream>>>(
      tmp2, Wf, embT2g2, cst + GD2_, cst + G02_, x, dinv, tmp1, 64,
      nullptr, nullptr, N, NG);
  // ---- GCN layer 2 aggregate ----
  gather_k<<<grid, blk, 0, stream>>>(tmp1, rowptr, col, dinv, g2B, tmp2, N);

  // ---- fused pbt+rec1 (two halves), BN1 stats ----
  gemmt_gv_k<false, true><<<NT, blk, 0, stream>>>(
      tmp2, Wr, embT2rA, cst + RD1_, cst + RD0_, x, nullptr, Z, 128,
      cst + S1_, cst + Q1_, N, NG);
  gemmt_gv_k<false, true><<<NT, blk, 0, stream>>>(
      tmp2, Wr + 64 * 64, embT2rB, cst + RD1_ + 64, cst + RD0_ + 64, x, nullptr,
      Z + 64, 128, cst + S1_ + 64, cst + Q1_ + 64, N, NG);
  bnparam_k<<<1, 128, 0, stream>>>(cst + S1_, cst + Q1_, rg1, rbe1,
                                   cst + SC1_, cst + SH1_, 128, 1.0f / (float)N);
  // ---- rec2: K=128 single kernel, BN on input, bias + BN2 stats ----
  gemmt_rec2_k<<<NT, blk, 0, stream>>>(Z, rW2, rb2, cst + SC1_, cst + SH1_,
                                       z2, cst + S2_, cst + Q2_, N);
  bnparam_k<<<1, 64, 0, stream>>>(cst + S2_, cst + Q2_, rg2, rbe2,
                                  cst + SC2_, cst + SH2_, 64, 1.0f / (float)N);
  rec3_k<<<grid, blk, 0, stream>>>(z2, cst + SC2_, cst + SH2_, rW3, rb3, outp, N);
}

// Round 12
// 485.852 us; speedup vs baseline: 1.7786x; 1.1715x over previous
//
#include <hip/hip_runtime.h>

// ---------------------------------------------------------------------------
// GNN_Disentangle on MI355X. H=64 fixed. f32 throughout.
//
// Round-12 changes (three independent levers):
//  1. gather_k: 8-edge batches, 4 independent accumulators -> 2x memory-level
//     parallelism (r11 counters: VALUBusy 20%, 47% HBM -> latency-bound bet).
//  2. bscan_k (1-block serial 256-iter scan over 256KB) -> scan1b_k (256
//     blocks, one LDS scan per bucket) + scan2b_k (tiny cross-bucket scan).
//  3. rec1 two half-passes merged into gemmt_rec1_k: X staged once, W halves
//     looped with X resident (accA+accB = 64 regs under the 128 cap).
// Everything else identical to round 11.
// ---------------------------------------------------------------------------

#define GS_GRID 2048
#define GS_BLK  256

enum { A1_=0, A0_=64, C1_=128, C0_=192, D1_=256, D0_=320,
       S1_=384, Q1_=512, SC1_=640, SH1_=768,
       S2_=896, Q2_=960, SC2_=1024, SH2_=1088,
       GD1_=1152, GA1_=1216, G00_=1280,
       GD2_=1344, G02_=1408, RD1_=1472, RD0_=1600, CST_FLOATS=2048 };

__device__ __forceinline__ float wave_sum64(float v) {
#pragma unroll
  for (int o = 32; o; o >>= 1) v += __shfl_xor(v, o, 64);
  return v;
}

__device__ __forceinline__ int rfl(int v) { return __builtin_amdgcn_readfirstlane(v); }

__device__ __forceinline__ float rlane(float v, int k) {
  return __int_as_float(__builtin_amdgcn_readlane(__float_as_int(v), k));
}

// ---------------- CSR build: bucketed counting sort ----------------
// bucket = dst >> 10; requires N <= 262144 (<=256 buckets).

__global__ __launch_bounds__(256) void hist_k(const int* __restrict__ ei,
                                              int* __restrict__ hist, int E) {
  __shared__ int h[256];
  const int t = threadIdx.x;
  h[t] = 0;
  __syncthreads();
  const int per = (E + gridDim.x - 1) / gridDim.x;
  const int beg = blockIdx.x * per, end = min(E, beg + per);
  for (int i = beg + t; i < end; i += 256)
    atomicAdd(&h[ei[E + i] >> 10], 1);
  __syncthreads();
  hist[blockIdx.x * 256 + t] = h[t];
}

// one block per bucket b: exclusive scan of hist[j][b] over j (256 blocks)
__global__ void scan1b_k(int* __restrict__ hist, int* __restrict__ bsum) {
  __shared__ int sc[256];
  const int t = threadIdx.x;        // block index j within bucket
  const int b = blockIdx.x;         // bucket id
  int v = hist[t * 256 + b];
  sc[t] = v; __syncthreads();
  for (int o = 1; o < 256; o <<= 1) {
    int x = sc[t]; if (t >= o) x += sc[t - o];
    __syncthreads(); sc[t] = x; __syncthreads();
  }
  hist[t * 256 + b] = sc[t] - v;    // block-exclusive offset within bucket
  if (t == 255) bsum[b] = sc[t];    // bucket total
}

// tiny cross-bucket exclusive scan
__global__ void scan2b_k(const int* __restrict__ bsum, int* __restrict__ bucketBase,
                         int* __restrict__ rowptrN, int E) {
  __shared__ int sc[256];
  const int t = threadIdx.x;
  int v = bsum[t];
  sc[t] = v; __syncthreads();
  for (int o = 1; o < 256; o <<= 1) {
    int x = sc[t]; if (t >= o) x += sc[t - o];
    __syncthreads(); sc[t] = x; __syncthreads();
  }
  bucketBase[t] = sc[t] - v;
  if (t == 255) { bucketBase[256] = sc[t]; rowptrN[0] = E; }
}

__global__ __launch_bounds__(256) void bucket_k(const int* __restrict__ ei,
                                                const int* __restrict__ hist,
                                                const int* __restrict__ bucketBase,
                                                int2* __restrict__ eb, int E) {
  __shared__ int cur[256];
  const int t = threadIdx.x;
  cur[t] = hist[blockIdx.x * 256 + t] + bucketBase[t];
  __syncthreads();
  const int per = (E + gridDim.x - 1) / gridDim.x;
  const int beg = blockIdx.x * per, end = min(E, beg + per);
  for (int i = beg + t; i < end; i += 256) {
    int s = ei[i], d = ei[E + i];
    int pos = atomicAdd(&cur[d >> 10], 1);
    eb[pos] = make_int2(s, d);
  }
}

__global__ __launch_bounds__(256) void csr_k(const int2* __restrict__ eb,
                                             const int* __restrict__ bucketBase,
                                             int* __restrict__ rowptr, float* __restrict__ dinv,
                                             int* __restrict__ col, int N) {
  __shared__ int cnt[1024];
  __shared__ int base[1024];
  __shared__ int red[256];
  const int t = threadIdx.x;
  const int k = blockIdx.x;
  const int nodeBeg = k << 10;
  const int segBeg = bucketBase[k], segEnd = bucketBase[k + 1];
#pragma unroll
  for (int j = t; j < 1024; j += 256) cnt[j] = 0;
  __syncthreads();
  for (int i = segBeg + t; i < segEnd; i += 256)
    atomicAdd(&cnt[eb[i].y & 1023], 1);
  __syncthreads();
  int c0 = cnt[4 * t], c1 = cnt[4 * t + 1], c2 = cnt[4 * t + 2], c3 = cnt[4 * t + 3];
  int ts = c0 + c1 + c2 + c3;
  red[t] = ts; __syncthreads();
  for (int o = 1; o < 256; o <<= 1) {
    int x = red[t]; if (t >= o) x += red[t - o];
    __syncthreads(); red[t] = x; __syncthreads();
  }
  int off = red[t] - ts;
  base[4 * t] = off;
  base[4 * t + 1] = off + c0;
  base[4 * t + 2] = off + c0 + c1;
  base[4 * t + 3] = off + c0 + c1 + c2;
#pragma unroll
  for (int u = 0; u < 4; ++u) {
    int j = 4 * t + u;
    int node = nodeBeg + j;
    if (node < N) {
      rowptr[node] = segBeg + base[j];
      dinv[node] = rsqrtf((float)(cnt[j] + 1));   // +1 self loop
    }
  }
  __syncthreads();
  cnt[4 * t] = base[4 * t]; cnt[4 * t + 1] = base[4 * t + 1];
  cnt[4 * t + 2] = base[4 * t + 2]; cnt[4 * t + 3] = base[4 * t + 3];
  __syncthreads();
  for (int i = segBeg + t; i < segEnd; i += 256) {
    int2 e = eb[i];
    int pos = atomicAdd(&cnt[e.y & 1023], 1);
    col[segBeg + pos] = e.x;
  }
}

// ---------------- tiny const GEMVs ----------------
__global__ void consts1_k(const float* __restrict__ pbtW, const float* __restrict__ pertW,
                          const float* __restrict__ pertB, const float* __restrict__ etW,
                          const float* __restrict__ basW, const float* __restrict__ basB,
                          const float* __restrict__ etB, float* __restrict__ cst) {
  int h = threadIdx.x;  // 64
  float a1 = 0, a0 = 0, c1 = 0, c0 = 0;
  for (int k = 0; k < 64; ++k) {
    float wp = pbtW[h * 128 + k];
    a1 = fmaf(wp, pertW[k], a1);
    a0 = fmaf(wp, pertB[k], a0);
    float we = etW[h * 128 + 64 + k];
    c1 = fmaf(we, basW[k], c1);
    c0 = fmaf(we, basB[k], c0);
  }
  cst[A1_ + h] = a1; cst[A0_ + h] = a0; cst[C1_ + h] = c1; cst[C0_ + h] = c0 + etB[h];
}

__global__ void consts2_k(const float* __restrict__ pbtW, const float* __restrict__ pbtB,
                          float* __restrict__ cst) {
  int h = threadIdx.x;  // 64
  float d1 = 0, d0 = 0;
  for (int k = 0; k < 64; ++k) {
    float w = pbtW[h * 128 + 64 + k];
    d1 = fmaf(w, cst[C1_ + k], d1);
    d0 = fmaf(w, cst[C0_ + k], d0);
  }
  cst[D1_ + h] = d1; cst[D0_ + h] = d0 + pbtB[h];
}

// gd1 = g1W@d1, ga1 = g1W@a1, g00 = g1W@(d0+a0)   (layer-1 m fold)
__global__ void consts3_k(const float* __restrict__ g1W, float* __restrict__ cst) {
  int h = threadIdx.x;  // 64
  float gd1 = 0, ga1 = 0, g00 = 0;
  for (int k = 0; k < 64; ++k) {
    float w = g1W[h * 64 + k];
    gd1 = fmaf(w, cst[D1_ + k], gd1);
    ga1 = fmaf(w, cst[A1_ + k], ga1);
    g00 = fmaf(w, cst[D0_ + k] + cst[A0_ + k], g00);
  }
  cst[GD1_ + h] = gd1; cst[GA1_ + h] = ga1; cst[G00_ + h] = g00;
}

// GD2 = g2W@d1, G02 = g2W@d0   (layer-2 m fold)
__global__ void consts5_k(const float* __restrict__ g2W, float* __restrict__ cst) {
  int h = threadIdx.x;  // 64
  float a = 0, b = 0;
  for (int k = 0; k < 64; ++k) {
    float w = g2W[h * 64 + k];
    a = fmaf(w, cst[D1_ + k], a);
    b = fmaf(w, cst[D0_ + k], b);
  }
  cst[GD2_ + h] = a; cst[G02_ + h] = b;
}

// RD1 = rW1@d1, RD0 = rW1@d0 + rb1   (pbt-into-rec1 fold), 128 channels
__global__ void consts6_k(const float* __restrict__ rW1, const float* __restrict__ rb1,
                          float* __restrict__ cst) {
  int c = threadIdx.x;  // 128
  float a = 0, b = 0;
  for (int k = 0; k < 64; ++k) {
    float w = rW1[c * 64 + k];
    a = fmaf(w, cst[D1_ + k], a);
    b = fmaf(w, cst[D0_ + k], b);
  }
  cst[RD1_ + c] = a; cst[RD0_ + c] = b + rb1[c];
}

// Wf = g2W @ pbtW[:, :64]  (64x64); Wr = rW1 @ pbtW[:, :64]  (128x64)
__global__ void constsW_k(const float* __restrict__ g2W, const float* __restrict__ rW1,
                          const float* __restrict__ pbtW,
                          float* __restrict__ Wf, float* __restrict__ Wr) {
  const int t = threadIdx.x;
  for (int e = t; e < 4096; e += 256) {
    int c = e >> 6, j = e & 63;
    float s = 0.f;
    for (int h = 0; h < 64; ++h) s = fmaf(g2W[c * 64 + h], pbtW[h * 128 + j], s);
    Wf[e] = s;
  }
  for (int e = t; e < 8192; e += 256) {
    int c = e >> 6, j = e & 63;
    float s = 0.f;
    for (int h = 0; h < 64; ++h) s = fmaf(rW1[c * 64 + h], pbtW[h * 128 + j], s);
    Wr[e] = s;
  }
}

// ---------------- per-gene tables ----------------
template <bool NORM>
__global__ __launch_bounds__(256) void geneT_k(const float* __restrict__ in,
                                               const float* __restrict__ W, int ldw,
                                               float* __restrict__ out, int NG) {
  const int lane = threadIdx.x & 63;
  const int wid = blockIdx.x * 4 + (threadIdx.x >> 6);
  const int nw = gridDim.x * 4;
  float w[64];
#pragma unroll
  for (int j = 0; j < 16; ++j) {
    float4 v = *reinterpret_cast<const float4*>(W + lane * ldw + 4 * j);
    w[4 * j] = v.x; w[4 * j + 1] = v.y; w[4 * j + 2] = v.z; w[4 * j + 3] = v.w;
  }
  for (int g = wid; g < NG; g += nw) {
    float e = in[g * 64 + lane];
    if (NORM) {
      float sq = wave_sum64(e * e);
      float nrm = sqrtf(sq);
      float s = nrm > 1.f ? 1.f / nrm : 1.f;
      e *= s;
    }
    float acc = 0.f;
#pragma unroll
    for (int k = 0; k < 64; ++k) acc = fmaf(w[k], rlane(e, k), acc);
    out[g * 64 + lane] = acc;
  }
}

// ---------------- elementwise m1 ----------------
__global__ __launch_bounds__(256) void m1_k(const float* __restrict__ x,
                                            const float* __restrict__ embTm1,
                                            const float* __restrict__ dinv,
                                            const float* __restrict__ cst,
                                            float* __restrict__ m1, int N, int NG) {
  int total = N * 16;
  for (int idx = blockIdx.x * blockDim.x + threadIdx.x; idx < total;
       idx += gridDim.x * blockDim.x) {
    int n = idx >> 4, q = idx & 15;
    int g = n % NG;
    float x0 = x[2 * n], x1 = x[2 * n + 1], dn = dinv[n];
    float4 em = *reinterpret_cast<const float4*>(embTm1 + g * 64 + q * 4);
    float4 gd1 = *reinterpret_cast<const float4*>(cst + GD1_ + q * 4);
    float4 ga1 = *reinterpret_cast<const float4*>(cst + GA1_ + q * 4);
    float4 g00 = *reinterpret_cast<const float4*>(cst + G00_ + q * 4);
    float4 mv;
    mv.x = dn * (fmaf(x0, gd1.x, fmaf(x1, ga1.x, em.x + g00.x)));
    mv.y = dn * (fmaf(x0, gd1.y, fmaf(x1, ga1.y, em.y + g00.y)));
    mv.z = dn * (fmaf(x0, gd1.z, fmaf(x1, ga1.z, em.z + g00.z)));
    mv.w = dn * (fmaf(x0, gd1.w, fmaf(x1, ga1.w, em.w + g00.w)));
    reinterpret_cast<float4*>(m1)[idx] = mv;
  }
}

// ---------------- register-tiled GEMM (r10 skeleton) ----------------
#define XS_STRIDE 130
#define WS_STRIDE 68
#define OS_STRIDE 68
#define OS_WORDS  (128 * OS_STRIDE)          // 8704 (>= 64*XS_STRIDE = 8320)
#define WS_WORDS  (64 * WS_STRIDE)           // 4352
#define LDS_WORDS (OS_WORDS + WS_WORDS + 128)

// gv variant: epilogue o = [dinv*] (acc + tbl[g] + x0*cA + cB).
template <bool MUL_D>
__global__ __launch_bounds__(256, 4) void gemmt_gv_k(
    const float* __restrict__ in,        // [N,64]
    const float* __restrict__ W,         // [64][64] row-major
    const float* __restrict__ tbl,       // [NG,64]
    const float* __restrict__ cA,        // [64]
    const float* __restrict__ cB,        // [64]
    const float* __restrict__ x,         // [N,2]
    const float* __restrict__ dinv,
    float* __restrict__ out, int ldout, int N, int NG) {
  __shared__ float lds[LDS_WORDS];
  float* Xs = lds;
  float* Ws = lds + OS_WORDS;
  const int t = threadIdx.x;
  const int base = blockIdx.x << 7;

#pragma unroll
  for (int c = 0; c < 16; ++c) {
    int lin = c * 256 + t;
    int cw = lin >> 6, kw = lin & 63;
    Ws[kw * WS_STRIDE + cw] = W[cw * 64 + kw];
  }
#pragma unroll
  for (int c = 0; c < 8; ++c) {
    int lin = c * 256 + t;
    int nl = lin >> 4, k4 = lin & 15;
    int row = base + nl; if (row >= N) row = N - 1;
    float4 v = *reinterpret_cast<const float4*>(in + (size_t)row * 64 + 4 * k4);
    Xs[(4 * k4 + 0) * XS_STRIDE + nl] = v.x;
    Xs[(4 * k4 + 1) * XS_STRIDE + nl] = v.y;
    Xs[(4 * k4 + 2) * XS_STRIDE + nl] = v.z;
    Xs[(4 * k4 + 3) * XS_STRIDE + nl] = v.w;
  }
  __syncthreads();

  const int ng = t & 31;
  const int c0 = (t >> 5) * 8;
  float acc[8][4];
#pragma unroll
  for (int i = 0; i < 8; ++i)
#pragma unroll
    for (int j = 0; j < 4; ++j) acc[i][j] = 0.f;
#pragma unroll 4
  for (int k = 0; k < 64; ++k) {
    float4 wa = *reinterpret_cast<const float4*>(Ws + k * WS_STRIDE + c0);
    float4 wb = *reinterpret_cast<const float4*>(Ws + k * WS_STRIDE + c0 + 4);
    float2 xa = *reinterpret_cast<const float2*>(Xs + k * XS_STRIDE + 2 * ng);
    float2 xb = *reinterpret_cast<const float2*>(Xs + k * XS_STRIDE + 2 * ng + 64);
    const float w8[8] = {wa.x, wa.y, wa.z, wa.w, wb.x, wb.y, wb.z, wb.w};
    const float x4[4] = {xa.x, xa.y, xb.x, xb.y};
#pragma unroll
    for (int ci = 0; ci < 8; ++ci)
#pragma unroll
      for (int xi = 0; xi < 4; ++xi)
        acc[ci][xi] = fmaf(w8[ci], x4[xi], acc[ci][xi]);
  }
  __syncthreads();

  const int nd[4] = {2 * ng, 2 * ng + 1, 2 * ng + 64, 2 * ng + 65};
#pragma unroll
  for (int ci = 0; ci < 8; ++ci) {
    Xs[nd[0] * OS_STRIDE + c0 + ci] = acc[ci][0];
    Xs[nd[1] * OS_STRIDE + c0 + ci] = acc[ci][1];
    Xs[nd[2] * OS_STRIDE + c0 + ci] = acc[ci][2];
    Xs[nd[3] * OS_STRIDE + c0 + ci] = acc[ci][3];
  }
  __syncthreads();

  const int q = t & 15;
  const float4 a4 = *reinterpret_cast<const float4*>(cA + 4 * q);
  const float4 b4 = *reinterpret_cast<const float4*>(cB + 4 * q);
#pragma unroll
  for (int c = 0; c < 8; ++c) {
    int nl = c * 16 + (t >> 4);
    int n = base + nl;
    if (n < N) {
      float4 o = *reinterpret_cast<const float4*>(Xs + nl * OS_STRIDE + 4 * q);
      int g = n % NG;
      float4 tg = *reinterpret_cast<const float4*>(tbl + (size_t)g * 64 + 4 * q);
      float x0 = x[2 * n];
      o.x += fmaf(x0, a4.x, tg.x + b4.x);
      o.y += fmaf(x0, a4.y, tg.y + b4.y);
      o.z += fmaf(x0, a4.z, tg.z + b4.z);
      o.w += fmaf(x0, a4.w, tg.w + b4.w);
      if (MUL_D) {
        float dv = dinv[n];
        o.x *= dv; o.y *= dv; o.z *= dv; o.w *= dv;
      }
      *reinterpret_cast<float4*>(out + (size_t)n * ldout + 4 * q) = o;
    }
  }
}

// rec1 merged: one X stage, two W halves (Wr [128][64]), gv epilogue + BN1
// stats per half. Z out ld=128. accA+accB = 64 loop-carried registers.
__global__ __launch_bounds__(256, 4) void gemmt_rec1_k(
    const float* __restrict__ in,        // [N,64] (gathered t2)
    const float* __restrict__ Wr,        // [128][64]
    const float* __restrict__ tblA, const float* __restrict__ tblB,   // [NG,64]
    const float* __restrict__ cA,        // RD1 [128]
    const float* __restrict__ cB,        // RD0 [128]
    const float* __restrict__ x,
    float* __restrict__ Z,               // [N,128]
    float* __restrict__ sums, float* __restrict__ sqs,   // [128] each
    int N, int NG) {
  __shared__ float lds[LDS_WORDS];
  float* Xs = lds;
  float* Ws = lds + OS_WORDS;
  float* sred = lds + OS_WORDS + WS_WORDS;
  const int t = threadIdx.x;
  const int base = blockIdx.x << 7;
  if (t < 128) sred[t] = 0.f;

  // stage W half A + X
#pragma unroll
  for (int c = 0; c < 16; ++c) {
    int lin = c * 256 + t;
    int cw = lin >> 6, kw = lin & 63;
    Ws[kw * WS_STRIDE + cw] = Wr[cw * 64 + kw];
  }
#pragma unroll
  for (int c = 0; c < 8; ++c) {
    int lin = c * 256 + t;
    int nl = lin >> 4, k4 = lin & 15;
    int row = base + nl; if (row >= N) row = N - 1;
    float4 v = *reinterpret_cast<const float4*>(in + (size_t)row * 64 + 4 * k4);
    Xs[(4 * k4 + 0) * XS_STRIDE + nl] = v.x;
    Xs[(4 * k4 + 1) * XS_STRIDE + nl] = v.y;
    Xs[(4 * k4 + 2) * XS_STRIDE + nl] = v.z;
    Xs[(4 * k4 + 3) * XS_STRIDE + nl] = v.w;
  }
  __syncthreads();

  const int ng = t & 31;
  const int c0 = (t >> 5) * 8;
  float accA[8][4], accB[8][4];
#pragma unroll
  for (int i = 0; i < 8; ++i)
#pragma unroll
    for (int j = 0; j < 4; ++j) { accA[i][j] = 0.f; accB[i][j] = 0.f; }

#pragma unroll 4
  for (int k = 0; k < 64; ++k) {
    float4 wa = *reinterpret_cast<const float4*>(Ws + k * WS_STRIDE + c0);
    float4 wb = *reinterpret_cast<const float4*>(Ws + k * WS_STRIDE + c0 + 4);
    float2 xa = *reinterpret_cast<const float2*>(Xs + k * XS_STRIDE + 2 * ng);
    float2 xb = *reinterpret_cast<const float2*>(Xs + k * XS_STRIDE + 2 * ng + 64);
    const float w8[8] = {wa.x, wa.y, wa.z, wa.w, wb.x, wb.y, wb.z, wb.w};
    const float x4[4] = {xa.x, xa.y, xb.x, xb.y};
#pragma unroll
    for (int ci = 0; ci < 8; ++ci)
#pragma unroll
      for (int xi = 0; xi < 4; ++xi)
        accA[ci][xi] = fmaf(w8[ci], x4[xi], accA[ci][xi]);
  }
  __syncthreads();          // half-A reads done before Ws overwrite
#pragma unroll
  for (int c = 0; c < 16; ++c) {
    int lin = c * 256 + t;
    int cw = lin >> 6, kw = lin & 63;
    Ws[kw * WS_STRIDE + cw] = Wr[(64 + cw) * 64 + kw];
  }
  __syncthreads();
#pragma unroll 4
  for (int k = 0; k < 64; ++k) {
    float4 wa = *reinterpret_cast<const float4*>(Ws + k * WS_STRIDE + c0);
    float4 wb = *reinterpret_cast<const float4*>(Ws + k * WS_STRIDE + c0 + 4);
    float2 xa = *reinterpret_cast<const float2*>(Xs + k * XS_STRIDE + 2 * ng);
    float2 xb = *reinterpret_cast<const float2*>(Xs + k * XS_STRIDE + 2 * ng + 64);
    const float w8[8] = {wa.x, wa.y, wa.z, wa.w, wb.x, wb.y, wb.z, wb.w};
    const float x4[4] = {xa.x, xa.y, xb.x, xb.y};
#pragma unroll
    for (int ci = 0; ci < 8; ++ci)
#pragma unroll
      for (int xi = 0; xi < 4; ++xi)
        accB[ci][xi] = fmaf(w8[ci], x4[xi], accB[ci][xi]);
  }
  __syncthreads();          // X reads done; Xs region now reusable as Os

  const int nd[4] = {2 * ng, 2 * ng + 1, 2 * ng + 64, 2 * ng + 65};
  const int q = t & 15;

  // ---- half A: transpose, copy-out, stats ----
#pragma unroll
  for (int ci = 0; ci < 8; ++ci) {
    Xs[nd[0] * OS_STRIDE + c0 + ci] = accA[ci][0];
    Xs[nd[1] * OS_STRIDE + c0 + ci] = accA[ci][1];
    Xs[nd[2] * OS_STRIDE + c0 + ci] = accA[ci][2];
    Xs[nd[3] * OS_STRIDE + c0 + ci] = accA[ci][3];
  }
  __syncthreads();
  {
    const float4 a4 = *reinterpret_cast<const float4*>(cA + 4 * q);
    const float4 b4 = *reinterpret_cast<const float4*>(cB + 4 * q);
    float4 s4 = make_float4(0.f, 0.f, 0.f, 0.f);
    float4 q4 = make_float4(0.f, 0.f, 0.f, 0.f);
#pragma unroll
    for (int c = 0; c < 8; ++c) {
      int nl = c * 16 + (t >> 4);
      int n = base + nl;
      if (n < N) {
        float4 o = *reinterpret_cast<const float4*>(Xs + nl * OS_STRIDE + 4 * q);
        int g = n % NG;
        float4 tg = *reinterpret_cast<const float4*>(tblA + (size_t)g * 64 + 4 * q);
        float x0 = x[2 * n];
        o.x += fmaf(x0, a4.x, tg.x + b4.x);
        o.y += fmaf(x0, a4.y, tg.y + b4.y);
        o.z += fmaf(x0, a4.z, tg.z + b4.z);
        o.w += fmaf(x0, a4.w, tg.w + b4.w);
        *reinterpret_cast<float4*>(Z + (size_t)n * 128 + 4 * q) = o;
        s4.x += o.x; s4.y += o.y; s4.z += o.z; s4.w += o.w;
        q4.x += o.x * o.x; q4.y += o.y * o.y; q4.z += o.z * o.z; q4.w += o.w * o.w;
      }
    }
    atomicAdd(&sred[4 * q + 0], s4.x); atomicAdd(&sred[4 * q + 1], s4.y);
    atomicAdd(&sred[4 * q + 2], s4.z); atomicAdd(&sred[4 * q + 3], s4.w);
    atomicAdd(&sred[64 + 4 * q + 0], q4.x); atomicAdd(&sred[64 + 4 * q + 1], q4.y);
    atomicAdd(&sred[64 + 4 * q + 2], q4.z); atomicAdd(&sred[64 + 4 * q + 3], q4.w);
  }
  __syncthreads();
  if (t < 64) {
    atomicAdd(&sums[t], sred[t]);
    atomicAdd(&sqs[t], sred[64 + t]);
  }
  __syncthreads();
  if (t < 128) sred[t] = 0.f;
  __syncthreads();

  // ---- half B: transpose, copy-out, stats ----
#pragma unroll
  for (int ci = 0; ci < 8; ++ci) {
    Xs[nd[0] * OS_STRIDE + c0 + ci] = accB[ci][0];
    Xs[nd[1] * OS_STRIDE + c0 + ci] = accB[ci][1];
    Xs[nd[2] * OS_STRIDE + c0 + ci] = accB[ci][2];
    Xs[nd[3] * OS_STRIDE + c0 + ci] = accB[ci][3];
  }
  __syncthreads();
  {
    const float4 a4 = *reinterpret_cast<const float4*>(cA + 64 + 4 * q);
    const float4 b4 = *reinterpret_cast<const float4*>(cB + 64 + 4 * q);
    float4 s4 = make_float4(0.f, 0.f, 0.f, 0.f);
    float4 q4 = make_float4(0.f, 0.f, 0.f, 0.f);
#pragma unroll
    for (int c = 0; c < 8; ++c) {
      int nl = c * 16 + (t >> 4);
      int n = base + nl;
      if (n < N) {
        float4 o = *reinterpret_cast<const float4*>(Xs + nl * OS_STRIDE + 4 * q);
        int g = n % NG;
        float4 tg = *reinterpret_cast<const float4*>(tblB + (size_t)g * 64 + 4 * q);
        float x0 = x[2 * n];
        o.x += fmaf(x0, a4.x, tg.x + b4.x);
        o.y += fmaf(x0, a4.y, tg.y + b4.y);
        o.z += fmaf(x0, a4.z, tg.z + b4.z);
        o.w += fmaf(x0, a4.w, tg.w + b4.w);
        *reinterpret_cast<float4*>(Z + (size_t)n * 128 + 64 + 4 * q) = o;
        s4.x += o.x; s4.y += o.y; s4.z += o.z; s4.w += o.w;
        q4.x += o.x * o.x; q4.y += o.y * o.y; q4.z += o.z * o.z; q4.w += o.w * o.w;
      }
    }
    atomicAdd(&sred[4 * q + 0], s4.x); atomicAdd(&sred[4 * q + 1], s4.y);
    atomicAdd(&sred[4 * q + 2], s4.z); atomicAdd(&sred[4 * q + 3], s4.w);
    atomicAdd(&sred[64 + 4 * q + 0], q4.x); atomicAdd(&sred[64 + 4 * q + 1], q4.y);
    atomicAdd(&sred[64 + 4 * q + 2], q4.z); atomicAdd(&sred[64 + 4 * q + 3], q4.w);
  }
  __syncthreads();
  if (t < 64) {
    atomicAdd(&sums[64 + t], sred[t]);
    atomicAdd(&sqs[64 + t], sred[64 + t]);
  }
}

// rec2 variant: K=128 via two stage+accumulate rounds (unchanged from r11).
__global__ __launch_bounds__(256, 4) void gemmt_rec2_k(
    const float* __restrict__ Z,         // [N,128]
    const float* __restrict__ W,         // rW2 [64][128]
    const float* __restrict__ b,
    const float* __restrict__ bnsc, const float* __restrict__ bnsh,
    float* __restrict__ out,             // [N,64]
    float* __restrict__ sums, float* __restrict__ sqs, int N) {
  __shared__ float lds[LDS_WORDS];
  float* Xs = lds;
  float* Ws = lds + OS_WORDS;
  float* sred = lds + OS_WORDS + WS_WORDS;
  const int t = threadIdx.x;
  const int base = blockIdx.x << 7;
  if (t < 128) sred[t] = 0.f;

  const int ng = t & 31;
  const int c0 = (t >> 5) * 8;
  float acc[8][4];
#pragma unroll
  for (int i = 0; i < 8; ++i)
#pragma unroll
    for (int j = 0; j < 4; ++j) acc[i][j] = 0.f;

  for (int half = 0; half < 2; ++half) {
    if (half) __syncthreads();
    const int ko = half * 64;
#pragma unroll
    for (int c = 0; c < 16; ++c) {
      int lin = c * 256 + t;
      int cw = lin >> 6, kw = lin & 63;
      Ws[kw * WS_STRIDE + cw] = W[cw * 128 + ko + kw];
    }
#pragma unroll
    for (int c = 0; c < 8; ++c) {
      int lin = c * 256 + t;
      int nl = lin >> 4, k4 = lin & 15;
      int row = base + nl; if (row >= N) row = N - 1;
      float4 v = *reinterpret_cast<const float4*>(Z + (size_t)row * 128 + ko + 4 * k4);
      float4 sc = *reinterpret_cast<const float4*>(bnsc + ko + 4 * k4);
      float4 sh = *reinterpret_cast<const float4*>(bnsh + ko + 4 * k4);
      v.x = fmaxf(fmaf(v.x, sc.x, sh.x), 0.f);
      v.y = fmaxf(fmaf(v.y, sc.y, sh.y), 0.f);
      v.z = fmaxf(fmaf(v.z, sc.z, sh.z), 0.f);
      v.w = fmaxf(fmaf(v.w, sc.w, sh.w), 0.f);
      Xs[(4 * k4 + 0) * XS_STRIDE + nl] = v.x;
      Xs[(4 * k4 + 1) * XS_STRIDE + nl] = v.y;
      Xs[(4 * k4 + 2) * XS_STRIDE + nl] = v.z;
      Xs[(4 * k4 + 3) * XS_STRIDE + nl] = v.w;
    }
    __syncthreads();
#pragma unroll 4
    for (int k = 0; k < 64; ++k) {
      float4 wa = *reinterpret_cast<const float4*>(Ws + k * WS_STRIDE + c0);
      float4 wb = *reinterpret_cast<const float4*>(Ws + k * WS_STRIDE + c0 + 4);
      float2 xa = *reinterpret_cast<const float2*>(Xs + k * XS_STRIDE + 2 * ng);
      float2 xb = *reinterpret_cast<const float2*>(Xs + k * XS_STRIDE + 2 * ng + 64);
      const float w8[8] = {wa.x, wa.y, wa.z, wa.w, wb.x, wb.y, wb.z, wb.w};
      const float x4[4] = {xa.x, xa.y, xb.x, xb.y};
#pragma unroll
      for (int ci = 0; ci < 8; ++ci)
#pragma unroll
        for (int xi = 0; xi < 4; ++xi)
          acc[ci][xi] = fmaf(w8[ci], x4[xi], acc[ci][xi]);
    }
  }
  __syncthreads();

  const int nd[4] = {2 * ng, 2 * ng + 1, 2 * ng + 64, 2 * ng + 65};
#pragma unroll
  for (int ci = 0; ci < 8; ++ci) {
    Xs[nd[0] * OS_STRIDE + c0 + ci] = acc[ci][0];
    Xs[nd[1] * OS_STRIDE + c0 + ci] = acc[ci][1];
    Xs[nd[2] * OS_STRIDE + c0 + ci] = acc[ci][2];
    Xs[nd[3] * OS_STRIDE + c0 + ci] = acc[ci][3];
  }
  __syncthreads();

  const int q = t & 15;
  const float4 bb = *reinterpret_cast<const float4*>(b + 4 * q);
  float4 s4 = make_float4(0.f, 0.f, 0.f, 0.f);
  float4 q4 = make_float4(0.f, 0.f, 0.f, 0.f);
#pragma unroll
  for (int c = 0; c < 8; ++c) {
    int nl = c * 16 + (t >> 4);
    int n = base + nl;
    if (n < N) {
      float4 o = *reinterpret_cast<const float4*>(Xs + nl * OS_STRIDE + 4 * q);
      o.x += bb.x; o.y += bb.y; o.z += bb.z; o.w += bb.w;
      *reinterpret_cast<float4*>(out + (size_t)n * 64 + 4 * q) = o;
      s4.x += o.x; s4.y += o.y; s4.z += o.z; s4.w += o.w;
      q4.x += o.x * o.x; q4.y += o.y * o.y; q4.z += o.z * o.z; q4.w += o.w * o.w;
    }
  }
  atomicAdd(&sred[4 * q + 0], s4.x); atomicAdd(&sred[4 * q + 1], s4.y);
  atomicAdd(&sred[4 * q + 2], s4.z); atomicAdd(&sred[4 * q + 3], s4.w);
  atomicAdd(&sred[64 + 4 * q + 0], q4.x); atomicAdd(&sred[64 + 4 * q + 1], q4.y);
  atomicAdd(&sred[64 + 4 * q + 2], q4.z); atomicAdd(&sred[64 + 4 * q + 3], q4.w);
  __syncthreads();
  if (t < 64) {
    atomicAdd(&sums[t], sred[t]);
    atomicAdd(&sqs[t], sred[64 + t]);
  }
}

// ---------------- CSR gather (8-edge batches, 4 accumulators) ----------------
__global__ __launch_bounds__(256) void gather_k(const float* __restrict__ m,
                                                const int* __restrict__ rowptr,
                                                const int* __restrict__ col,
                                                const float* __restrict__ dinv,
                                                const float* __restrict__ bias,
                                                float* __restrict__ out, int N) {
  const int lane = threadIdx.x & 63;
  const int wid = blockIdx.x * 4 + (threadIdx.x >> 6);
  const int nw = gridDim.x * 4;
  const float b = bias[lane];
  for (int n = wid; n < N; n += nw) {
    const int nn = rfl(n);
    const float dn = dinv[nn];
    float a0 = m[(size_t)nn * 64 + lane];   // self term (m' carries src dinv)
    float a1 = 0.f, a2 = 0.f, a3 = 0.f;
    const int beg = rfl(rowptr[nn]), end = rfl(rowptr[nn + 1]);
    for (int base = beg; base < end; base += 64) {
      const int rem = end - base;
      const int kk = rem < 64 ? rem : 64;
      int cv = (lane < kk) ? col[base + lane] : 0;   // coalesced chunk
      int k = 0;
      for (; k + 7 < kk; k += 8) {                   // 8 outstanding misses
        int i0 = __shfl(cv, k, 64),     i1 = __shfl(cv, k + 1, 64);
        int i2 = __shfl(cv, k + 2, 64), i3 = __shfl(cv, k + 3, 64);
        int i4 = __shfl(cv, k + 4, 64), i5 = __shfl(cv, k + 5, 64);
        int i6 = __shfl(cv, k + 6, 64), i7 = __shfl(cv, k + 7, 64);
        float v0 = m[(size_t)i0 * 64 + lane];
        float v1 = m[(size_t)i1 * 64 + lane];
        float v2 = m[(size_t)i2 * 64 + lane];
        float v3 = m[(size_t)i3 * 64 + lane];
        float v4 = m[(size_t)i4 * 64 + lane];
        float v5 = m[(size_t)i5 * 64 + lane];
        float v6 = m[(size_t)i6 * 64 + lane];
        float v7 = m[(size_t)i7 * 64 + lane];
        a0 += v0 + v4; a1 += v1 + v5; a2 += v2 + v6; a3 += v3 + v7;
      }
      for (; k + 1 < kk; k += 2) {
        int i0 = __shfl(cv, k, 64), i1 = __shfl(cv, k + 1, 64);
        float v0 = m[(size_t)i0 * 64 + lane];
        float v1 = m[(size_t)i1 * 64 + lane];
        a0 += v0; a1 += v1;
      }
      if (k < kk) a0 += m[(size_t)__shfl(cv, k, 64) * 64 + lane];
    }
    float acc = (a0 + a1) + (a2 + a3);
    out[(size_t)nn * 64 + lane] = fmaxf(fmaf(dn, acc, b), 0.f);
  }
}

__global__ void bnparam_k(const float* __restrict__ sums, const float* __restrict__ sqs,
                          const float* __restrict__ g, const float* __restrict__ be,
                          float* __restrict__ scale, float* __restrict__ shift, int C,
                          float invN) {
  int t = threadIdx.x;
  if (t < C) {
    float mu = sums[t] * invN;
    float var = fmaxf(sqs[t] * invN - mu * mu, 0.f);
    float sc = g[t] * rsqrtf(var + 1e-5f);
    scale[t] = sc;
    shift[t] = be[t] - mu * sc;
  }
}

__global__ __launch_bounds__(256) void rec3_k(const float* __restrict__ z2,
                                              const float* __restrict__ scale,
                                              const float* __restrict__ shift,
                                              const float* __restrict__ W3,
                                              const float* __restrict__ b3,
                                              float* __restrict__ out, int N) {
  const int lane = threadIdx.x & 63;
  const int wid = blockIdx.x * 4 + (threadIdx.x >> 6);
  const int nw = gridDim.x * 4;
  const float sc = scale[lane], sh = shift[lane], w = W3[lane], b = b3[0];
  for (int n = wid; n < N; n += nw) {
    float v = z2[(size_t)n * 64 + lane];
    v = fmaxf(fmaf(v, sc, sh), 0.f) * w;
    v = wave_sum64(v);
    if (lane == 0) out[n] = v + b;
  }
}

// ---------------------------------------------------------------------------
extern "C" void kernel_launch(void* const* d_in, const int* in_sizes, int n_in,
                              void* d_out, int out_size, void* d_ws, size_t ws_size,
                              hipStream_t stream) {
  const float* x     = (const float*)d_in[0];
  const int*   ei    = (const int*)d_in[1];
  const float* pertW = (const float*)d_in[2];
  const float* pertB = (const float*)d_in[3];
  const float* basW  = (const float*)d_in[4];
  const float* basB  = (const float*)d_in[5];
  const float* embTb = (const float*)d_in[6];
  const float* etW   = (const float*)d_in[7];
  const float* etB   = (const float*)d_in[8];
  const float* pbtW  = (const float*)d_in[9];
  const float* pbtB  = (const float*)d_in[10];
  const float* g1W   = (const float*)d_in[11];
  const float* g1B   = (const float*)d_in[12];
  const float* g2W   = (const float*)d_in[13];
  const float* g2B   = (const float*)d_in[14];
  const float* rW1   = (const float*)d_in[15];
  const float* rb1   = (const float*)d_in[16];
  const float* rg1   = (const float*)d_in[17];
  const float* rbe1  = (const float*)d_in[18];
  const float* rW2   = (const float*)d_in[19];
  const float* rb2   = (const float*)d_in[20];
  const float* rg2   = (const float*)d_in[21];
  const float* rbe2  = (const float*)d_in[22];
  const float* rW3   = (const float*)d_in[23];
  const float* rb3   = (const float*)d_in[24];
  float* outp = (float*)d_out;

  const int N  = in_sizes[0] / 2;
  const int E  = in_sizes[1] / 2;
  const int NG = in_sizes[6] / 64;
  const int NB = (N + 1023) >> 10;   // bucket count, <= 256 for N <= 262144
  const int NT = (N + 127) >> 7;     // gemmt tiles

  // ---- workspace layout (f32/int32, all 256B-aligned) ----
  char* p = (char*)d_ws;
  float* cst    = (float*)p; p += CST_FLOATS * 4;
  int*   hist   = (int*)p;   p += 256 * 256 * 4;
  int*   bb     = (int*)p;   p += 1024;            // 257 ints used
  int*   bsum   = (int*)p;   p += 1024;            // 256 ints used
  int*   rowptr = (int*)p;   p += (size_t)(N + 64) * 4;
  float* dinv   = (float*)p; p += (size_t)N * 4;
  int*   col    = (int*)p;   p += (size_t)E * 4;
  float* Wf     = (float*)p; p += 4096 * 4;        // g2W @ pbtW_a
  float* Wr     = (float*)p; p += 8192 * 4;        // rW1 @ pbtW_a
  float* embT   = (float*)p; p += (size_t)NG * 64 * 4;   // reused as embTm1
  float* embT2  = (float*)p; p += (size_t)NG * 64 * 4;
  float* embT2g2= (float*)p; p += (size_t)NG * 64 * 4;
  float* embT2rA= (float*)p; p += (size_t)NG * 64 * 4;
  float* embT2rB= (float*)p; p += (size_t)NG * 64 * 4;
  float* z2buf  = (float*)p; p += (size_t)N * 64 * 4;
  float* hb     = (float*)p; p += (size_t)N * 64 * 4;
  float* tmp1   = (float*)p; p += (size_t)N * 64 * 4;
  float* tmp2   = (float*)p; p += (size_t)N * 64 * 4;
  float* Z = hb;              // [N,128] overlay on hb+tmp1 (contiguous);
                              // input tmp2 never aliases Z (no race)
  float* z2 = z2buf;
  float* embTm1 = embT;       // embT dead after embT2 is built
  int2*  eb = (int2*)tmp2;    // bucket-sorted edges; dead before gather uses tmp2

  dim3 blk(GS_BLK), grid(GS_GRID);

  // ---- per-call init ----
  hipMemsetAsync(cst, 0, CST_FLOATS * 4, stream);   // also zeroes BN sums

  // ---- graph setup: bucketed counting sort -> CSR ----
  hist_k<<<256, 256, 0, stream>>>(ei, hist, E);
  scan1b_k<<<256, 256, 0, stream>>>(hist, bsum);
  scan2b_k<<<1, 256, 0, stream>>>(bsum, bb, rowptr + N, E);
  bucket_k<<<256, 256, 0, stream>>>(ei, hist, bb, eb, E);
  csr_k<<<NB, 256, 0, stream>>>(eb, bb, rowptr, dinv, col, N);

  // ---- front-end algebra ----
  consts1_k<<<1, 64, 0, stream>>>(pbtW, pertW, pertB, etW, basW, basB, etB, cst);
  consts2_k<<<1, 64, 0, stream>>>(pbtW, pbtB, cst);
  consts3_k<<<1, 64, 0, stream>>>(g1W, cst);
  consts5_k<<<1, 64, 0, stream>>>(g2W, cst);
  consts6_k<<<1, 128, 0, stream>>>(rW1, rb1, cst);
  constsW_k<<<1, 256, 0, stream>>>(g2W, rW1, pbtW, Wf, Wr);
  geneT_k<true><<<256, 256, 0, stream>>>(embTb, etW, 128, embT, NG);
  geneT_k<false><<<256, 256, 0, stream>>>(embT, pbtW + 64, 128, embT2, NG);
  geneT_k<false><<<256, 256, 0, stream>>>(embT2, g1W, 64, embTm1, NG);
  geneT_k<false><<<256, 256, 0, stream>>>(embT2, g2W, 64, embT2g2, NG);
  geneT_k<false><<<256, 256, 0, stream>>>(embT2, rW1, 64, embT2rA, NG);
  geneT_k<false><<<256, 256, 0, stream>>>(embT2, rW1 + 64 * 64, 64, embT2rB, NG);
  m1_k<<<grid, blk, 0, stream>>>(x, embTm1, dinv, cst, tmp1, N, NG);

  // ---- GCN layer 1 aggregate ----
  gather_k<<<grid, blk, 0, stream>>>(tmp1, rowptr, col, dinv, g1B, tmp2, N);
  // ---- fused pbt+GCN2-m: m2 = dinv*(Wf·t + embT2g2[g] + x0*GD2 + G02) ----
  gemmt_gv_k<true><<<NT, blk, 0, stream>>>(
      tmp2, Wf, embT2g2, cst + GD2_, cst + G02_, x, dinv, tmp1, 64, N, NG);
  // ---- GCN layer 2 aggregate ----
  gather_k<<<grid, blk, 0, stream>>>(tmp1, rowptr, col, dinv, g2B, tmp2, N);

  // ---- fused pbt+rec1 (both halves, one kernel), BN1 stats ----
  gemmt_rec1_k<<<NT, blk, 0, stream>>>(
      tmp2, Wr, embT2rA, embT2rB, cst + RD1_, cst + RD0_, x, Z,
      cst + S1_, cst + Q1_, N, NG);
  bnparam_k<<<1, 128, 0, stream>>>(cst + S1_, cst + Q1_, rg1, rbe1,
                                   cst + SC1_, cst + SH1_, 128, 1.0f / (float)N);
  // ---- rec2: K=128 single kernel, BN on input, bias + BN2 stats ----
  gemmt_rec2_k<<<NT, blk, 0, stream>>>(Z, rW2, rb2, cst + SC1_, cst + SH1_,
                                       z2, cst + S2_, cst + Q2_, N);
  bnparam_k<<<1, 64, 0, stream>>>(cst + S2_, cst + Q2_, rg2, rbe2,
                                  cst + SC2_, cst + SH2_, 64, 1.0f / (float)N);
  rec3_k<<<grid, blk, 0, stream>>>(z2, cst + SC2_, cst + SH2_, rW3, rb3, outp, N);
}